// Round 1
// baseline (619.990 us; speedup 1.0000x reference)
//
#include <hip/hip_runtime.h>
#include <cstdint>
#include <cstddef>

typedef short short8 __attribute__((ext_vector_type(8)));
typedef float f32x4 __attribute__((ext_vector_type(4)));
typedef unsigned short ushort_t;

#define D_MODEL 1024
#define D_FF    2816
#define SEQ     2048
#define BATCH   2
#define NHEADS  16
#define DK      64
#define NTOK    (BATCH*SEQ)   // 4096

__device__ __forceinline__ float bf2f(ushort_t u) {
  return __builtin_bit_cast(float, (unsigned int)u << 16);
}
__device__ __forceinline__ ushort_t f2bf(float f) {
  unsigned int x = __builtin_bit_cast(unsigned int, f);
  x += 0x7fffu + ((x >> 16) & 1u);   // round-to-nearest-even
  return (ushort_t)(x >> 16);
}

// async global->LDS, 16B per lane. LDS dest = wave-uniform base + lane*16.
__device__ __forceinline__ void gld16(const ushort_t* g, ushort_t* l) {
  __builtin_amdgcn_global_load_lds(
      (const __attribute__((address_space(1))) unsigned int*)g,
      (__attribute__((address_space(3))) unsigned int*)l,
      16, 0, 0);
}

// ---------------- fp32 -> bf16 convert ----------------
__global__ __launch_bounds__(256) void convert_f32_bf16(
    const float* __restrict__ src, ushort_t* __restrict__ dst, int n4) {
  int i = blockIdx.x * 256 + threadIdx.x;
  if (i >= n4) return;
  float4 v = ((const float4*)src)[i];
  ushort4 o;
  o.x = f2bf(v.x); o.y = f2bf(v.y); o.z = f2bf(v.z); o.w = f2bf(v.w);
  ((ushort4*)dst)[i] = o;
}

// ---------------- RMSNorm (row of 1024) ----------------
__global__ __launch_bounds__(256) void rmsnorm_kernel(
    const float* __restrict__ x, const float* __restrict__ g, ushort_t* __restrict__ out) {
  int row = blockIdx.x;
  int tid = threadIdx.x;
  float4 v = ((const float4*)(x + (size_t)row * D_MODEL))[tid];
  float ss = v.x*v.x + v.y*v.y + v.z*v.z + v.w*v.w;
#pragma unroll
  for (int off = 1; off < 64; off <<= 1) ss += __shfl_xor(ss, off);
  __shared__ float wsum[4];
  if ((tid & 63) == 0) wsum[tid >> 6] = ss;
  __syncthreads();
  float total = wsum[0] + wsum[1] + wsum[2] + wsum[3];
  float rinv = rsqrtf(total * (1.0f / D_MODEL) + 1e-5f);
  float4 gv = ((const float4*)g)[tid];
  ushort4 o;
  o.x = f2bf(v.x * gv.x * rinv);
  o.y = f2bf(v.y * gv.y * rinv);
  o.z = f2bf(v.z * gv.z * rinv);
  o.w = f2bf(v.w * gv.w * rinv);
  ((ushort4*)(out + (size_t)row * D_MODEL))[tid] = o;
}

// ---------------- GEMM: C[M,N] = A[M,K] * B[N,K]^T ----------------
// m97 structure: 128x128 tile, BK=32, 4 waves each 64x64, global_load_lds w=16.
struct GemmArgs {
  const ushort_t* A;
  const ushort_t* B0; const ushort_t* B1; const ushort_t* B2;
  void* C0; void* C1; void* C2;
  const float* resid;   // EPI==1
  int M, N, K;
};

template<int EPI>  // 0: store bf16; 1: store fp32 = acc + resid
__global__ __launch_bounds__(256) void gemm128(GemmArgs args) {
  const ushort_t* B = blockIdx.z == 0 ? args.B0 : (blockIdx.z == 1 ? args.B1 : args.B2);
  void* C = blockIdx.z == 0 ? args.C0 : (blockIdx.z == 1 ? args.C1 : args.C2);
  const int N = args.N, K = args.K;
  __shared__ __align__(16) ushort_t sA[128 * 32];
  __shared__ __align__(16) ushort_t sB[128 * 32];
  const int tid  = threadIdx.x;
  const int w    = tid >> 6;
  const int lane = tid & 63;
  const int col  = lane & 15;
  const int quad = lane >> 4;
  const int waveM = (w >> 1) * 64;
  const int waveN = (w & 1) * 64;
  const int bm = blockIdx.y * 128;
  const int bn = blockIdx.x * 128;

  f32x4 acc[4][4] = {};

  const int srow = tid >> 2;           // 0..63
  const int scol = (tid & 3) * 8;
  const ushort_t* gA = args.A + (size_t)(bm + srow) * K + scol;
  const ushort_t* gB = B      + (size_t)(bn + srow) * K + scol;
  ushort_t* lA = sA + tid * 8;         // byte off = tid*16
  ushort_t* lB = sB + tid * 8;
  const size_t rstep = (size_t)64 * K;

  for (int k0 = 0; k0 < K; k0 += 32) {
    gld16(gA + k0,         lA);
    gld16(gA + k0 + rstep, lA + 2048);   // rows 64..127 -> +4096 B
    gld16(gB + k0,         lB);
    gld16(gB + k0 + rstep, lB + 2048);
    __syncthreads();                     // drains vmcnt -> LDS ready
    short8 af[4], bf[4];
#pragma unroll
    for (int mi = 0; mi < 4; mi++)
      af[mi] = *(const short8*)&sA[(waveM + mi * 16 + col) * 32 + quad * 8];
#pragma unroll
    for (int ni = 0; ni < 4; ni++)
      bf[ni] = *(const short8*)&sB[(waveN + ni * 16 + col) * 32 + quad * 8];
#pragma unroll
    for (int mi = 0; mi < 4; mi++)
#pragma unroll
      for (int ni = 0; ni < 4; ni++)
        acc[mi][ni] = __builtin_amdgcn_mfma_f32_16x16x32_bf16(af[mi], bf[ni], acc[mi][ni], 0, 0, 0);
    __syncthreads();                     // all reads done before next stage
  }

#pragma unroll
  for (int mi = 0; mi < 4; mi++) {
    int r0 = bm + waveM + mi * 16 + quad * 4;
#pragma unroll
    for (int ni = 0; ni < 4; ni++) {
      int c0 = bn + waveN + ni * 16 + col;
#pragma unroll
      for (int r = 0; r < 4; r++) {
        size_t idx = (size_t)(r0 + r) * N + c0;
        if (EPI == 0) ((ushort_t*)C)[idx] = f2bf(acc[mi][ni][r]);
        else          ((float*)C)[idx]    = acc[mi][ni][r] + args.resid[idx];
      }
    }
  }
}

// ---------------- RoPE (q,k in place), one wave per (b,s,h) ----------------
__global__ __launch_bounds__(256) void rope_kernel(
    ushort_t* __restrict__ q, ushort_t* __restrict__ k) {
  int item = blockIdx.x * 4 + (threadIdx.x >> 6);   // 0..65535
  int lane = threadIdx.x & 63;
  int h = item & 15;
  int s = (item >> 4) & (SEQ - 1);
  int b = item >> 15;
  size_t idx = ((size_t)(b * SEQ + s)) * D_MODEL + h * DK + lane;
  int p = lane >> 1;
  // inv = 10000^(-2p/64) = exp(-(p/32)*ln(10000))
  float inv = expf(-(float)p * (9.210340372f / 32.0f));
  float ang = (float)s * inv;
  float cs = cosf(ang), sn = sinf(ang);
  float qv = bf2f(q[idx]);
  float kv = bf2f(k[idx]);
  float qp = __shfl_xor(qv, 1);
  float kp = __shfl_xor(kv, 1);
  float sgn = (lane & 1) ? sn : -sn;   // even: x*c - x1*s ; odd: x*c + x0*s
  q[idx] = f2bf(qv * cs + qp * sgn);
  k[idx] = f2bf(kv * cs + kp * sgn);
}

// ---------------- V transpose: [B,S,H*dk] -> [B,H,dk,S] ----------------
__global__ __launch_bounds__(256) void vtrans_kernel(
    const ushort_t* __restrict__ v, ushort_t* __restrict__ vt) {
  int bh = blockIdx.y;
  int b = bh >> 4, h = bh & 15;
  int s0 = blockIdx.x * 64;
  __shared__ ushort_t tile[64][65];
  for (int i = threadIdx.x; i < 64 * 64; i += 256) {
    int sl = i >> 6, dl = i & 63;
    tile[dl][sl] = v[((size_t)(b * SEQ + s0 + sl)) * D_MODEL + h * DK + dl];
  }
  __syncthreads();
  for (int i = threadIdx.x; i < 64 * 64; i += 256) {
    int dl = i >> 6, sl = i & 63;
    vt[((size_t)bh * DK + dl) * SEQ + s0 + sl] = tile[dl][sl];
  }
}

// ---------------- flash attention, causal ----------------
// grid (S/64, B*H); wave w handles q rows s0 = bx*64 + w*16.
__global__ __launch_bounds__(256) void attn_kernel(
    const ushort_t* __restrict__ q, const ushort_t* __restrict__ k,
    const ushort_t* __restrict__ vt, ushort_t* __restrict__ out) {
  int bh = blockIdx.y;
  int b = bh >> 4, h = bh & 15;
  int w = threadIdx.x >> 6, lane = threadIdx.x & 63;
  int col = lane & 15, quad = lane >> 4;
  int s0 = blockIdx.x * 64 + w * 16;

  const size_t base = ((size_t)(b * SEQ)) * D_MODEL + h * DK;
  short8 qf[2];
#pragma unroll
  for (int kk = 0; kk < 2; kk++)
    qf[kk] = *(const short8*)&q[base + (size_t)(s0 + col) * D_MODEL + kk * 32 + quad * 8];

  f32x4 o[4] = {};
  float m_i[4], l_i[4];
#pragma unroll
  for (int r = 0; r < 4; r++) { m_i[r] = -__builtin_inff(); l_i[r] = 0.f; }

  __shared__ __align__(16) ushort_t pbuf[4][16][32];

  int ntiles = (s0 + 16 + 31) >> 5;
  for (int jt = 0; jt < ntiles; jt++) {
    int skey = jt * 32;
    f32x4 S0 = {0.f, 0.f, 0.f, 0.f}, S1 = {0.f, 0.f, 0.f, 0.f};
#pragma unroll
    for (int kk = 0; kk < 2; kk++) {
      short8 kf0 = *(const short8*)&k[base + (size_t)(skey + col) * D_MODEL + kk * 32 + quad * 8];
      short8 kf1 = *(const short8*)&k[base + (size_t)(skey + 16 + col) * D_MODEL + kk * 32 + quad * 8];
      S0 = __builtin_amdgcn_mfma_f32_16x16x32_bf16(qf[kk], kf0, S0, 0, 0, 0);
      S1 = __builtin_amdgcn_mfma_f32_16x16x32_bf16(qf[kk], kf1, S1, 0, 0, 0);
    }
    float s0v[4], s1v[4];
#pragma unroll
    for (int r = 0; r < 4; r++) { s0v[r] = S0[r] * 0.125f; s1v[r] = S1[r] * 0.125f; }
    if (skey + 31 > s0) {   // diagonal tile: mask
#pragma unroll
      for (int r = 0; r < 4; r++) {
        int qrow = s0 + quad * 4 + r;
        if (skey + col > qrow)      s0v[r] = -__builtin_inff();
        if (skey + 16 + col > qrow) s1v[r] = -__builtin_inff();
      }
    }
    float alpha[4];
#pragma unroll
    for (int r = 0; r < 4; r++) {
      float mt = fmaxf(s0v[r], s1v[r]);
#pragma unroll
      for (int off = 1; off < 16; off <<= 1) mt = fmaxf(mt, __shfl_xor(mt, off));
      float mn = fmaxf(m_i[r], mt);
      alpha[r] = __expf(m_i[r] - mn);
      m_i[r] = mn;
      float p0 = __expf(s0v[r] - mn);
      float p1 = __expf(s1v[r] - mn);
      float rs = p0 + p1;
#pragma unroll
      for (int off = 1; off < 16; off <<= 1) rs += __shfl_xor(rs, off);
      l_i[r] = alpha[r] * l_i[r] + rs;
      pbuf[w][quad * 4 + r][col]      = f2bf(p0);
      pbuf[w][quad * 4 + r][col + 16] = f2bf(p1);
    }
    __builtin_amdgcn_s_waitcnt(0xC07F);   // lgkmcnt(0) only
    short8 pf = *(const short8*)&pbuf[w][col][quad * 8];
#pragma unroll
    for (int c2 = 0; c2 < 4; c2++) {
#pragma unroll
      for (int r = 0; r < 4; r++) o[c2][r] *= alpha[r];
      short8 vf = *(const short8*)&vt[((size_t)bh * DK + c2 * 16 + col) * SEQ + skey + quad * 8];
      o[c2] = __builtin_amdgcn_mfma_f32_16x16x32_bf16(pf, vf, o[c2], 0, 0, 0);
    }
  }
#pragma unroll
  for (int c2 = 0; c2 < 4; c2++)
#pragma unroll
    for (int r = 0; r < 4; r++) {
      int row = s0 + quad * 4 + r;
      out[((size_t)(b * SEQ) + row) * D_MODEL + h * DK + c2 * 16 + col] = f2bf(o[c2][r] / l_i[r]);
    }
}

// ---------------- SwiGLU elementwise: u = silu(u)*g ----------------
__global__ __launch_bounds__(256) void silu_mul_kernel(
    ushort_t* __restrict__ u, const ushort_t* __restrict__ g, int n8) {
  int i = blockIdx.x * 256 + threadIdx.x;
  if (i >= n8) return;
  short8 uv = ((const short8*)u)[i];
  short8 gv = ((const short8*)g)[i];
  short8 t;
#pragma unroll
  for (int j = 0; j < 8; j++) {
    float x = bf2f((ushort_t)uv[j]);
    float gg = bf2f((ushort_t)gv[j]);
    float s = x / (1.f + __expf(-x));
    t[j] = (short)f2bf(s * gg);
  }
  ((short8*)u)[i] = t;
}

// ---------------- launcher ----------------
extern "C" void kernel_launch(void* const* d_in, const int* in_sizes, int n_in,
                              void* d_out, int out_size, void* d_ws, size_t ws_size,
                              hipStream_t stream) {
  const float* x  = (const float*)d_in[0];
  const float* g1 = (const float*)d_in[1];
  const float* g2 = (const float*)d_in[2];
  const float* WQ = (const float*)d_in[3];
  const float* WK = (const float*)d_in[4];
  const float* WV = (const float*)d_in[5];
  const float* WO = (const float*)d_in[6];
  const float* W1 = (const float*)d_in[7];
  const float* W2 = (const float*)d_in[8];
  const float* W3 = (const float*)d_in[9];
  float* out = (float*)d_out;

  char* p = (char*)d_ws;
  auto alloc = [&](size_t bytes) {
    char* r = p; p += (bytes + 255) & ~(size_t)255; return r;
  };
  ushort_t* wq  = (ushort_t*)alloc((size_t)D_MODEL * D_MODEL * 2);
  ushort_t* wk  = (ushort_t*)alloc((size_t)D_MODEL * D_MODEL * 2);
  ushort_t* wv  = (ushort_t*)alloc((size_t)D_MODEL * D_MODEL * 2);
  ushort_t* wo  = (ushort_t*)alloc((size_t)D_MODEL * D_MODEL * 2);
  ushort_t* w1b = (ushort_t*)alloc((size_t)D_FF * D_MODEL * 2);
  ushort_t* w2b = (ushort_t*)alloc((size_t)D_FF * D_MODEL * 2);
  ushort_t* w3b = (ushort_t*)alloc((size_t)D_FF * D_MODEL * 2);
  ushort_t* h   = (ushort_t*)alloc((size_t)NTOK * D_MODEL * 2);   // also h2
  ushort_t* qb  = (ushort_t*)alloc((size_t)NTOK * D_MODEL * 2);
  ushort_t* kb  = (ushort_t*)alloc((size_t)NTOK * D_MODEL * 2);
  ushort_t* vb  = (ushort_t*)alloc((size_t)NTOK * D_MODEL * 2);   // later reused as attn out
  ushort_t* vtb = (ushort_t*)alloc((size_t)NTOK * D_MODEL * 2);
  float*    y   = (float*)   alloc((size_t)NTOK * D_MODEL * 4);
  ushort_t* ub  = (ushort_t*)alloc((size_t)NTOK * D_FF * 2);      // silu*g in place
  ushort_t* gb  = (ushort_t*)alloc((size_t)NTOK * D_FF * 2);

  const int n4_dd  = D_MODEL * D_MODEL / 4;   // 262144
  const int n4_fd  = D_FF * D_MODEL / 4;      // 720896
  convert_f32_bf16<<<n4_dd / 256, 256, 0, stream>>>(WQ, wq, n4_dd);
  convert_f32_bf16<<<n4_dd / 256, 256, 0, stream>>>(WK, wk, n4_dd);
  convert_f32_bf16<<<n4_dd / 256, 256, 0, stream>>>(WV, wv, n4_dd);
  convert_f32_bf16<<<n4_dd / 256, 256, 0, stream>>>(WO, wo, n4_dd);
  convert_f32_bf16<<<n4_fd / 256, 256, 0, stream>>>(W1, w1b, n4_fd);
  convert_f32_bf16<<<n4_fd / 256, 256, 0, stream>>>(W2, w2b, n4_fd);
  convert_f32_bf16<<<n4_fd / 256, 256, 0, stream>>>(W3, w3b, n4_fd);

  rmsnorm_kernel<<<NTOK, 256, 0, stream>>>(x, g1, h);

  GemmArgs a1{h, wq, wk, wv, qb, kb, vb, nullptr, NTOK, D_MODEL, D_MODEL};
  gemm128<0><<<dim3(D_MODEL / 128, NTOK / 128, 3), 256, 0, stream>>>(a1);

  rope_kernel<<<(BATCH * SEQ * NHEADS) / 4, 256, 0, stream>>>(qb, kb);
  vtrans_kernel<<<dim3(SEQ / 64, BATCH * NHEADS), 256, 0, stream>>>(vb, vtb);
  attn_kernel<<<dim3(SEQ / 64, BATCH * NHEADS), 256, 0, stream>>>(qb, kb, vtb, vb);

  GemmArgs a2{vb, wo, nullptr, nullptr, y, nullptr, nullptr, x, NTOK, D_MODEL, D_MODEL};
  gemm128<1><<<dim3(D_MODEL / 128, NTOK / 128, 1), 256, 0, stream>>>(a2);

  rmsnorm_kernel<<<NTOK, 256, 0, stream>>>(y, g2, h);

  GemmArgs a3{h, w1b, w3b, nullptr, ub, gb, nullptr, nullptr, NTOK, D_FF, D_MODEL};
  gemm128<0><<<dim3(D_FF / 128, NTOK / 128, 2), 256, 0, stream>>>(a3);

  silu_mul_kernel<<<(NTOK * D_FF / 8) / 256, 256, 0, stream>>>(ub, gb, NTOK * D_FF / 8);

  GemmArgs a4{ub, w2b, nullptr, nullptr, out, nullptr, nullptr, y, NTOK, D_MODEL, D_FF};
  gemm128<1><<<dim3(D_MODEL / 128, NTOK / 128, 1), 256, 0, stream>>>(a4);
}

// Round 2
// 551.629 us; speedup vs baseline: 1.1239x; 1.1239x over previous
//
#include <hip/hip_runtime.h>
#include <cstdint>
#include <cstddef>

typedef short short8 __attribute__((ext_vector_type(8)));
typedef float f32x4 __attribute__((ext_vector_type(4)));
typedef unsigned short ushort_t;

#define D_MODEL 1024
#define D_FF    2816
#define SEQ     2048
#define BATCH   2
#define NHEADS  16
#define DK      64
#define NTOK    (BATCH*SEQ)   // 4096

__device__ __forceinline__ float bf2f(ushort_t u) {
  return __builtin_bit_cast(float, (unsigned int)u << 16);
}
__device__ __forceinline__ ushort_t f2bf(float f) {
  unsigned int x = __builtin_bit_cast(unsigned int, f);
  x += 0x7fffu + ((x >> 16) & 1u);   // round-to-nearest-even
  return (ushort_t)(x >> 16);
}

// async global->LDS, 16B per lane. LDS dest = wave-uniform base + lane*16.
__device__ __forceinline__ void gld16(const ushort_t* g, ushort_t* l) {
  __builtin_amdgcn_global_load_lds(
      (const __attribute__((address_space(1))) unsigned int*)g,
      (__attribute__((address_space(3))) unsigned int*)l,
      16, 0, 0);
}

// ---------------- fp32 -> bf16 convert ----------------
__global__ __launch_bounds__(256) void convert_f32_bf16(
    const float* __restrict__ src, ushort_t* __restrict__ dst, int n4) {
  int i = blockIdx.x * 256 + threadIdx.x;
  if (i >= n4) return;
  float4 v = ((const float4*)src)[i];
  ushort4 o;
  o.x = f2bf(v.x); o.y = f2bf(v.y); o.z = f2bf(v.z); o.w = f2bf(v.w);
  ((ushort4*)dst)[i] = o;
}

// ---------------- RMSNorm (row of 1024) ----------------
__global__ __launch_bounds__(256) void rmsnorm_kernel(
    const float* __restrict__ x, const float* __restrict__ g, ushort_t* __restrict__ out) {
  int row = blockIdx.x;
  int tid = threadIdx.x;
  float4 v = ((const float4*)(x + (size_t)row * D_MODEL))[tid];
  float ss = v.x*v.x + v.y*v.y + v.z*v.z + v.w*v.w;
#pragma unroll
  for (int off = 1; off < 64; off <<= 1) ss += __shfl_xor(ss, off);
  __shared__ float wsum[4];
  if ((tid & 63) == 0) wsum[tid >> 6] = ss;
  __syncthreads();
  float total = wsum[0] + wsum[1] + wsum[2] + wsum[3];
  float rinv = rsqrtf(total * (1.0f / D_MODEL) + 1e-5f);
  float4 gv = ((const float4*)g)[tid];
  ushort4 o;
  o.x = f2bf(v.x * gv.x * rinv);
  o.y = f2bf(v.y * gv.y * rinv);
  o.z = f2bf(v.z * gv.z * rinv);
  o.w = f2bf(v.w * gv.w * rinv);
  ((ushort4*)(out + (size_t)row * D_MODEL))[tid] = o;
}

// ---------------- GEMM: C[M,N] = A[M,K] * B[N,K]^T ----------------
// m97 structure: 128x128 tile, BK=32, 4 waves each 64x64, global_load_lds w=16.
struct GemmArgs {
  const ushort_t* A;
  const ushort_t* B0; const ushort_t* B1; const ushort_t* B2;
  void* C0; void* C1; void* C2;
  const float* resid;   // EPI==1
  int M, N, K;
};

template<int EPI>  // 0: store bf16; 1: store fp32 = acc + resid
__global__ __launch_bounds__(256) void gemm128(GemmArgs args) {
  const ushort_t* B = blockIdx.z == 0 ? args.B0 : (blockIdx.z == 1 ? args.B1 : args.B2);
  void* C = blockIdx.z == 0 ? args.C0 : (blockIdx.z == 1 ? args.C1 : args.C2);
  const int N = args.N, K = args.K;
  __shared__ __align__(16) ushort_t sA[128 * 32];
  __shared__ __align__(16) ushort_t sB[128 * 32];
  const int tid  = threadIdx.x;
  const int w    = tid >> 6;
  const int lane = tid & 63;
  const int col  = lane & 15;
  const int quad = lane >> 4;
  const int waveM = (w >> 1) * 64;
  const int waveN = (w & 1) * 64;
  const int bm = blockIdx.y * 128;
  const int bn = blockIdx.x * 128;

  f32x4 acc[4][4] = {};

  const int srow = tid >> 2;           // 0..63
  const int scol = (tid & 3) * 8;
  const ushort_t* gA = args.A + (size_t)(bm + srow) * K + scol;
  const ushort_t* gB = B      + (size_t)(bn + srow) * K + scol;
  ushort_t* lA = sA + tid * 8;         // byte off = tid*16
  ushort_t* lB = sB + tid * 8;
  const size_t rstep = (size_t)64 * K;

  for (int k0 = 0; k0 < K; k0 += 32) {
    gld16(gA + k0,         lA);
    gld16(gA + k0 + rstep, lA + 2048);   // rows 64..127 -> +4096 B
    gld16(gB + k0,         lB);
    gld16(gB + k0 + rstep, lB + 2048);
    __syncthreads();                     // drains vmcnt -> LDS ready
    short8 af[4], bf[4];
#pragma unroll
    for (int mi = 0; mi < 4; mi++)
      af[mi] = *(const short8*)&sA[(waveM + mi * 16 + col) * 32 + quad * 8];
#pragma unroll
    for (int ni = 0; ni < 4; ni++)
      bf[ni] = *(const short8*)&sB[(waveN + ni * 16 + col) * 32 + quad * 8];
#pragma unroll
    for (int mi = 0; mi < 4; mi++)
#pragma unroll
      for (int ni = 0; ni < 4; ni++)
        acc[mi][ni] = __builtin_amdgcn_mfma_f32_16x16x32_bf16(af[mi], bf[ni], acc[mi][ni], 0, 0, 0);
    __syncthreads();                     // all reads done before next stage
  }

#pragma unroll
  for (int mi = 0; mi < 4; mi++) {
    int r0 = bm + waveM + mi * 16 + quad * 4;
#pragma unroll
    for (int ni = 0; ni < 4; ni++) {
      int c0 = bn + waveN + ni * 16 + col;
#pragma unroll
      for (int r = 0; r < 4; r++) {
        size_t idx = (size_t)(r0 + r) * N + c0;
        if (EPI == 0) ((ushort_t*)C)[idx] = f2bf(acc[mi][ni][r]);
        else          ((float*)C)[idx]    = acc[mi][ni][r] + args.resid[idx];
      }
    }
  }
}

// ---------------- RoPE (q,k in place), one wave per (b,s,h) ----------------
__global__ __launch_bounds__(256) void rope_kernel(
    ushort_t* __restrict__ q, ushort_t* __restrict__ k) {
  int item = blockIdx.x * 4 + (threadIdx.x >> 6);   // 0..65535
  int lane = threadIdx.x & 63;
  int h = item & 15;
  int s = (item >> 4) & (SEQ - 1);
  int b = item >> 15;
  size_t idx = ((size_t)(b * SEQ + s)) * D_MODEL + h * DK + lane;
  int p = lane >> 1;
  // inv = 10000^(-2p/64) = exp(-(p/32)*ln(10000))
  float inv = expf(-(float)p * (9.210340372f / 32.0f));
  float ang = (float)s * inv;
  float cs = cosf(ang), sn = sinf(ang);
  float qv = bf2f(q[idx]);
  float kv = bf2f(k[idx]);
  float qp = __shfl_xor(qv, 1);
  float kp = __shfl_xor(kv, 1);
  float sgn = (lane & 1) ? sn : -sn;   // even: x*c - x1*s ; odd: x*c + x0*s
  q[idx] = f2bf(qv * cs + qp * sgn);
  k[idx] = f2bf(kv * cs + kp * sgn);
}

// ---------------- V transpose: [B,S,H*dk] -> [B,H,dk,S] ----------------
__global__ __launch_bounds__(256) void vtrans_kernel(
    const ushort_t* __restrict__ v, ushort_t* __restrict__ vt) {
  int bh = blockIdx.y;
  int b = bh >> 4, h = bh & 15;
  int s0 = blockIdx.x * 64;
  __shared__ ushort_t tile[64][65];
  for (int i = threadIdx.x; i < 64 * 64; i += 256) {
    int sl = i >> 6, dl = i & 63;
    tile[dl][sl] = v[((size_t)(b * SEQ + s0 + sl)) * D_MODEL + h * DK + dl];
  }
  __syncthreads();
  for (int i = threadIdx.x; i < 64 * 64; i += 256) {
    int dl = i >> 6, sl = i & 63;
    vt[((size_t)bh * DK + dl) * SEQ + s0 + sl] = tile[dl][sl];
  }
}

// ---------------- flash attention, causal, intra-block split-K ----------------
// grid (128, B*H). Block handles ONE 16-row q-tile (longest-first order);
// 4 waves split the key range in 64-key tiles (jt = w, w+4, ...), then merge
// partials (o, m, l) across waves via LDS log-sum-exp. Merge wave w writes
// output head-dims [w*16, w*16+16).
__global__ __launch_bounds__(256) void attn_kernel(
    const ushort_t* __restrict__ q, const ushort_t* __restrict__ k,
    const ushort_t* __restrict__ vt, ushort_t* __restrict__ out) {
  const int bh = blockIdx.y;
  const int b = bh >> 4, h = bh & 15;
  const int w = threadIdx.x >> 6, lane = threadIdx.x & 63;
  const int col = lane & 15, quad = lane >> 4;
  const int t = 127 - blockIdx.x;        // longest-first for tail balance
  const int s0 = t * 16;

  const size_t base = ((size_t)(b * SEQ)) * D_MODEL + h * DK;
  short8 qf[2];
#pragma unroll
  for (int kk = 0; kk < 2; kk++)
    qf[kk] = *(const short8*)&q[base + (size_t)(s0 + col) * D_MODEL + kk * 32 + quad * 8];

  f32x4 o[4] = {};
  float m_i[4], l_i[4];
#pragma unroll
  for (int r = 0; r < 4; r++) { m_i[r] = -__builtin_inff(); l_i[r] = 0.f; }

  __shared__ __align__(16) ushort_t pbuf[4][16][72];   // stride 72: 16B-aligned b128 reads
  __shared__ __align__(16) float obuf[4][4][64][4];    // [wave][c2][lane][r]
  __shared__ float mbuf[4][16];
  __shared__ float lbuf[4][16];

  const int ntiles = (s0 + 16 + 63) >> 6;   // 64-key tiles covering [0, s0+16)
  for (int jt = w; jt < ntiles; jt += 4) {
    const int skey = jt * 64;
    f32x4 S[4] = {};
#pragma unroll
    for (int kk = 0; kk < 2; kk++) {
#pragma unroll
      for (int sub = 0; sub < 4; sub++) {
        short8 kf = *(const short8*)&k[base + (size_t)(skey + sub * 16 + col) * D_MODEL + kk * 32 + quad * 8];
        S[sub] = __builtin_amdgcn_mfma_f32_16x16x32_bf16(qf[kk], kf, S[sub], 0, 0, 0);
      }
    }
    float sv[4][4];
#pragma unroll
    for (int sub = 0; sub < 4; sub++)
#pragma unroll
      for (int r = 0; r < 4; r++) sv[sub][r] = S[sub][r] * 0.125f;
    if (skey + 63 > s0) {   // diagonal tile: causal mask
#pragma unroll
      for (int sub = 0; sub < 4; sub++)
#pragma unroll
        for (int r = 0; r < 4; r++)
          if (skey + sub * 16 + col > s0 + quad * 4 + r) sv[sub][r] = -__builtin_inff();
    }
    float alpha[4];
#pragma unroll
    for (int r = 0; r < 4; r++) {
      float mt = fmaxf(fmaxf(sv[0][r], sv[1][r]), fmaxf(sv[2][r], sv[3][r]));
#pragma unroll
      for (int off = 1; off < 16; off <<= 1) mt = fmaxf(mt, __shfl_xor(mt, off));
      float mn = fmaxf(m_i[r], mt);
      alpha[r] = __expf(m_i[r] - mn);
      m_i[r] = mn;
      float p0 = __expf(sv[0][r] - mn);
      float p1 = __expf(sv[1][r] - mn);
      float p2 = __expf(sv[2][r] - mn);
      float p3 = __expf(sv[3][r] - mn);
      float rs = (p0 + p1) + (p2 + p3);
#pragma unroll
      for (int off = 1; off < 16; off <<= 1) rs += __shfl_xor(rs, off);
      l_i[r] = alpha[r] * l_i[r] + rs;
      int row = quad * 4 + r;
      pbuf[w][row][col]      = f2bf(p0);
      pbuf[w][row][col + 16] = f2bf(p1);
      pbuf[w][row][col + 32] = f2bf(p2);
      pbuf[w][row][col + 48] = f2bf(p3);
    }
    __builtin_amdgcn_s_waitcnt(0xC07F);   // lgkmcnt(0): pbuf writes visible to own wave
    short8 pf0 = *(const short8*)&pbuf[w][col][quad * 8];
    short8 pf1 = *(const short8*)&pbuf[w][col][32 + quad * 8];
#pragma unroll
    for (int c2 = 0; c2 < 4; c2++) {
#pragma unroll
      for (int r = 0; r < 4; r++) o[c2][r] *= alpha[r];
      const ushort_t* vrow = &vt[((size_t)bh * DK + c2 * 16 + col) * SEQ + skey];
      short8 vf0 = *(const short8*)&vrow[quad * 8];
      short8 vf1 = *(const short8*)&vrow[32 + quad * 8];
      o[c2] = __builtin_amdgcn_mfma_f32_16x16x32_bf16(pf0, vf0, o[c2], 0, 0, 0);
      o[c2] = __builtin_amdgcn_mfma_f32_16x16x32_bf16(pf1, vf1, o[c2], 0, 0, 0);
    }
  }

  // ---- merge partials across the 4 waves ----
#pragma unroll
  for (int c2 = 0; c2 < 4; c2++)
    *(f32x4*)&obuf[w][c2][lane][0] = o[c2];
  if (col == 0) {
#pragma unroll
    for (int r = 0; r < 4; r++) {
      mbuf[w][quad * 4 + r] = m_i[r];
      lbuf[w][quad * 4 + r] = l_i[r];
    }
  }
  __syncthreads();

  float M[4], L[4], sc[4][4];   // sc[src wave][r]
#pragma unroll
  for (int r = 0; r < 4; r++) {
    int row = quad * 4 + r;
    float m0 = mbuf[0][row], m1 = mbuf[1][row], m2 = mbuf[2][row], m3 = mbuf[3][row];
    M[r] = fmaxf(fmaxf(m0, m1), fmaxf(m2, m3));
    float e0 = __expf(m0 - M[r]);
    float e1 = __expf(m1 - M[r]);
    float e2 = __expf(m2 - M[r]);
    float e3 = __expf(m3 - M[r]);
    sc[0][r] = e0; sc[1][r] = e1; sc[2][r] = e2; sc[3][r] = e3;
    L[r] = lbuf[0][row] * e0 + lbuf[1][row] * e1 + lbuf[2][row] * e2 + lbuf[3][row] * e3;
  }
  f32x4 oo = {};
#pragma unroll
  for (int wp = 0; wp < 4; wp++) {
    f32x4 tv = *(const f32x4*)&obuf[wp][w][lane][0];
#pragma unroll
    for (int r = 0; r < 4; r++) oo[r] += tv[r] * sc[wp][r];
  }
#pragma unroll
  for (int r = 0; r < 4; r++) {
    int row = s0 + quad * 4 + r;
    out[((size_t)(b * SEQ) + row) * D_MODEL + h * DK + w * 16 + col] = f2bf(oo[r] / L[r]);
  }
}

// ---------------- SwiGLU elementwise: u = silu(u)*g ----------------
__global__ __launch_bounds__(256) void silu_mul_kernel(
    ushort_t* __restrict__ u, const ushort_t* __restrict__ g, int n8) {
  int i = blockIdx.x * 256 + threadIdx.x;
  if (i >= n8) return;
  short8 uv = ((const short8*)u)[i];
  short8 gv = ((const short8*)g)[i];
  short8 t;
#pragma unroll
  for (int j = 0; j < 8; j++) {
    float x = bf2f((ushort_t)uv[j]);
    float gg = bf2f((ushort_t)gv[j]);
    float s = x / (1.f + __expf(-x));
    t[j] = (short)f2bf(s * gg);
  }
  ((short8*)u)[i] = t;
}

// ---------------- launcher ----------------
extern "C" void kernel_launch(void* const* d_in, const int* in_sizes, int n_in,
                              void* d_out, int out_size, void* d_ws, size_t ws_size,
                              hipStream_t stream) {
  const float* x  = (const float*)d_in[0];
  const float* g1 = (const float*)d_in[1];
  const float* g2 = (const float*)d_in[2];
  const float* WQ = (const float*)d_in[3];
  const float* WK = (const float*)d_in[4];
  const float* WV = (const float*)d_in[5];
  const float* WO = (const float*)d_in[6];
  const float* W1 = (const float*)d_in[7];
  const float* W2 = (const float*)d_in[8];
  const float* W3 = (const float*)d_in[9];
  float* out = (float*)d_out;

  char* p = (char*)d_ws;
  auto alloc = [&](size_t bytes) {
    char* r = p; p += (bytes + 255) & ~(size_t)255; return r;
  };
  ushort_t* wq  = (ushort_t*)alloc((size_t)D_MODEL * D_MODEL * 2);
  ushort_t* wk  = (ushort_t*)alloc((size_t)D_MODEL * D_MODEL * 2);
  ushort_t* wv  = (ushort_t*)alloc((size_t)D_MODEL * D_MODEL * 2);
  ushort_t* wo  = (ushort_t*)alloc((size_t)D_MODEL * D_MODEL * 2);
  ushort_t* w1b = (ushort_t*)alloc((size_t)D_FF * D_MODEL * 2);
  ushort_t* w2b = (ushort_t*)alloc((size_t)D_FF * D_MODEL * 2);
  ushort_t* w3b = (ushort_t*)alloc((size_t)D_FF * D_MODEL * 2);
  ushort_t* h   = (ushort_t*)alloc((size_t)NTOK * D_MODEL * 2);   // also h2
  ushort_t* qb  = (ushort_t*)alloc((size_t)NTOK * D_MODEL * 2);
  ushort_t* kb  = (ushort_t*)alloc((size_t)NTOK * D_MODEL * 2);
  ushort_t* vb  = (ushort_t*)alloc((size_t)NTOK * D_MODEL * 2);   // later reused as attn out
  ushort_t* vtb = (ushort_t*)alloc((size_t)NTOK * D_MODEL * 2);
  float*    y   = (float*)   alloc((size_t)NTOK * D_MODEL * 4);
  ushort_t* ub  = (ushort_t*)alloc((size_t)NTOK * D_FF * 2);      // silu*g in place
  ushort_t* gb  = (ushort_t*)alloc((size_t)NTOK * D_FF * 2);

  const int n4_dd  = D_MODEL * D_MODEL / 4;   // 262144
  const int n4_fd  = D_FF * D_MODEL / 4;      // 720896
  convert_f32_bf16<<<n4_dd / 256, 256, 0, stream>>>(WQ, wq, n4_dd);
  convert_f32_bf16<<<n4_dd / 256, 256, 0, stream>>>(WK, wk, n4_dd);
  convert_f32_bf16<<<n4_dd / 256, 256, 0, stream>>>(WV, wv, n4_dd);
  convert_f32_bf16<<<n4_dd / 256, 256, 0, stream>>>(WO, wo, n4_dd);
  convert_f32_bf16<<<n4_fd / 256, 256, 0, stream>>>(W1, w1b, n4_fd);
  convert_f32_bf16<<<n4_fd / 256, 256, 0, stream>>>(W2, w2b, n4_fd);
  convert_f32_bf16<<<n4_fd / 256, 256, 0, stream>>>(W3, w3b, n4_fd);

  rmsnorm_kernel<<<NTOK, 256, 0, stream>>>(x, g1, h);

  GemmArgs a1{h, wq, wk, wv, qb, kb, vb, nullptr, NTOK, D_MODEL, D_MODEL};
  gemm128<0><<<dim3(D_MODEL / 128, NTOK / 128, 3), 256, 0, stream>>>(a1);

  rope_kernel<<<(BATCH * SEQ * NHEADS) / 4, 256, 0, stream>>>(qb, kb);
  vtrans_kernel<<<dim3(SEQ / 64, BATCH * NHEADS), 256, 0, stream>>>(vb, vtb);
  attn_kernel<<<dim3(SEQ / 16, BATCH * NHEADS), 256, 0, stream>>>(qb, kb, vtb, vb);

  GemmArgs a2{vb, wo, nullptr, nullptr, y, nullptr, nullptr, x, NTOK, D_MODEL, D_MODEL};
  gemm128<1><<<dim3(D_MODEL / 128, NTOK / 128, 1), 256, 0, stream>>>(a2);

  rmsnorm_kernel<<<NTOK, 256, 0, stream>>>(y, g2, h);

  GemmArgs a3{h, w1b, w3b, nullptr, ub, gb, nullptr, nullptr, NTOK, D_FF, D_MODEL};
  gemm128<0><<<dim3(D_FF / 128, NTOK / 128, 2), 256, 0, stream>>>(a3);

  silu_mul_kernel<<<(NTOK * D_FF / 8) / 256, 256, 0, stream>>>(ub, gb, NTOK * D_FF / 8);

  GemmArgs a4{ub, w2b, nullptr, nullptr, out, nullptr, nullptr, y, NTOK, D_MODEL, D_FF};
  gemm128<1><<<dim3(D_MODEL / 128, NTOK / 128, 1), 256, 0, stream>>>(a4);
}

// Round 3
// 550.998 us; speedup vs baseline: 1.1252x; 1.0011x over previous
//
#include <hip/hip_runtime.h>
#include <cstdint>
#include <cstddef>

typedef short short8 __attribute__((ext_vector_type(8)));
typedef float f32x4 __attribute__((ext_vector_type(4)));
typedef unsigned short ushort_t;

#define D_MODEL 1024
#define D_FF    2816
#define SEQ     2048
#define BATCH   2
#define NHEADS  16
#define DK      64
#define NTOK    (BATCH*SEQ)   // 4096

__device__ __forceinline__ float bf2f(ushort_t u) {
  return __builtin_bit_cast(float, (unsigned int)u << 16);
}
__device__ __forceinline__ ushort_t f2bf(float f) {
  unsigned int x = __builtin_bit_cast(unsigned int, f);
  x += 0x7fffu + ((x >> 16) & 1u);   // round-to-nearest-even
  return (ushort_t)(x >> 16);
}

// async global->LDS, 16B per lane. LDS dest = wave-uniform base + lane*16.
__device__ __forceinline__ void gld16(const ushort_t* g, ushort_t* l) {
  __builtin_amdgcn_global_load_lds(
      (const __attribute__((address_space(1))) unsigned int*)g,
      (__attribute__((address_space(3))) unsigned int*)l,
      16, 0, 0);
}

// ---------------- fp32 -> bf16 convert ----------------
__global__ __launch_bounds__(256) void convert_f32_bf16(
    const float* __restrict__ src, ushort_t* __restrict__ dst, int n4) {
  int i = blockIdx.x * 256 + threadIdx.x;
  if (i >= n4) return;
  float4 v = ((const float4*)src)[i];
  ushort4 o;
  o.x = f2bf(v.x); o.y = f2bf(v.y); o.z = f2bf(v.z); o.w = f2bf(v.w);
  ((ushort4*)dst)[i] = o;
}

// ---------------- RMSNorm (row of 1024) ----------------
__global__ __launch_bounds__(256) void rmsnorm_kernel(
    const float* __restrict__ x, const float* __restrict__ g, ushort_t* __restrict__ out) {
  int row = blockIdx.x;
  int tid = threadIdx.x;
  float4 v = ((const float4*)(x + (size_t)row * D_MODEL))[tid];
  float ss = v.x*v.x + v.y*v.y + v.z*v.z + v.w*v.w;
#pragma unroll
  for (int off = 1; off < 64; off <<= 1) ss += __shfl_xor(ss, off);
  __shared__ float wsum[4];
  if ((tid & 63) == 0) wsum[tid >> 6] = ss;
  __syncthreads();
  float total = wsum[0] + wsum[1] + wsum[2] + wsum[3];
  float rinv = rsqrtf(total * (1.0f / D_MODEL) + 1e-5f);
  float4 gv = ((const float4*)g)[tid];
  ushort4 o;
  o.x = f2bf(v.x * gv.x * rinv);
  o.y = f2bf(v.y * gv.y * rinv);
  o.z = f2bf(v.z * gv.z * rinv);
  o.w = f2bf(v.w * gv.w * rinv);
  ((ushort4*)(out + (size_t)row * D_MODEL))[tid] = o;
}

// ---------------- GEMM: C[M,N] = A[M,K] * B[N,K]^T ----------------
// m97 structure: 128x128 tile, BK=32, 4 waves each 64x64, global_load_lds w=16.
struct GemmArgs {
  const ushort_t* A;
  const ushort_t* B0; const ushort_t* B1; const ushort_t* B2;
  void* C0; void* C1; void* C2;
  const float* resid;   // EPI==1
  int M, N, K;
};

template<int EPI>  // 0: store bf16; 1: store fp32 = acc + resid
__global__ __launch_bounds__(256) void gemm128(GemmArgs args) {
  const ushort_t* B = blockIdx.z == 0 ? args.B0 : (blockIdx.z == 1 ? args.B1 : args.B2);
  void* C = blockIdx.z == 0 ? args.C0 : (blockIdx.z == 1 ? args.C1 : args.C2);
  const int N = args.N, K = args.K;
  __shared__ __align__(16) ushort_t sA[128 * 32];
  __shared__ __align__(16) ushort_t sB[128 * 32];
  const int tid  = threadIdx.x;
  const int w    = tid >> 6;
  const int lane = tid & 63;
  const int col  = lane & 15;
  const int quad = lane >> 4;
  const int waveM = (w >> 1) * 64;
  const int waveN = (w & 1) * 64;
  const int bm = blockIdx.y * 128;
  const int bn = blockIdx.x * 128;

  f32x4 acc[4][4] = {};

  const int srow = tid >> 2;           // 0..63
  const int scol = (tid & 3) * 8;
  const ushort_t* gA = args.A + (size_t)(bm + srow) * K + scol;
  const ushort_t* gB = B      + (size_t)(bn + srow) * K + scol;
  ushort_t* lA = sA + tid * 8;         // byte off = tid*16
  ushort_t* lB = sB + tid * 8;
  const size_t rstep = (size_t)64 * K;

  for (int k0 = 0; k0 < K; k0 += 32) {
    gld16(gA + k0,         lA);
    gld16(gA + k0 + rstep, lA + 2048);   // rows 64..127 -> +4096 B
    gld16(gB + k0,         lB);
    gld16(gB + k0 + rstep, lB + 2048);
    __syncthreads();                     // drains vmcnt -> LDS ready
    short8 af[4], bf[4];
#pragma unroll
    for (int mi = 0; mi < 4; mi++)
      af[mi] = *(const short8*)&sA[(waveM + mi * 16 + col) * 32 + quad * 8];
#pragma unroll
    for (int ni = 0; ni < 4; ni++)
      bf[ni] = *(const short8*)&sB[(waveN + ni * 16 + col) * 32 + quad * 8];
#pragma unroll
    for (int mi = 0; mi < 4; mi++)
#pragma unroll
      for (int ni = 0; ni < 4; ni++)
        acc[mi][ni] = __builtin_amdgcn_mfma_f32_16x16x32_bf16(af[mi], bf[ni], acc[mi][ni], 0, 0, 0);
    __syncthreads();                     // all reads done before next stage
  }

#pragma unroll
  for (int mi = 0; mi < 4; mi++) {
    int r0 = bm + waveM + mi * 16 + quad * 4;
#pragma unroll
    for (int ni = 0; ni < 4; ni++) {
      int c0 = bn + waveN + ni * 16 + col;
#pragma unroll
      for (int r = 0; r < 4; r++) {
        size_t idx = (size_t)(r0 + r) * N + c0;
        if (EPI == 0) ((ushort_t*)C)[idx] = f2bf(acc[mi][ni][r]);
        else          ((float*)C)[idx]    = acc[mi][ni][r] + args.resid[idx];
      }
    }
  }
}

// ---------------- RoPE (q,k in place), one wave per (b,s,h) ----------------
__global__ __launch_bounds__(256) void rope_kernel(
    ushort_t* __restrict__ q, ushort_t* __restrict__ k) {
  int item = blockIdx.x * 4 + (threadIdx.x >> 6);   // 0..65535
  int lane = threadIdx.x & 63;
  int h = item & 15;
  int s = (item >> 4) & (SEQ - 1);
  int b = item >> 15;
  size_t idx = ((size_t)(b * SEQ + s)) * D_MODEL + h * DK + lane;
  int p = lane >> 1;
  // inv = 10000^(-2p/64) = exp(-(p/32)*ln(10000))
  float inv = expf(-(float)p * (9.210340372f / 32.0f));
  float ang = (float)s * inv;
  float cs = cosf(ang), sn = sinf(ang);
  float qv = bf2f(q[idx]);
  float kv = bf2f(k[idx]);
  float qp = __shfl_xor(qv, 1);
  float kp = __shfl_xor(kv, 1);
  float sgn = (lane & 1) ? sn : -sn;   // even: x*c - x1*s ; odd: x*c + x0*s
  q[idx] = f2bf(qv * cs + qp * sgn);
  k[idx] = f2bf(kv * cs + kp * sgn);
}

// ---------------- V transpose: [B,S,H*dk] -> [B,H,dk,S] ----------------
__global__ __launch_bounds__(256) void vtrans_kernel(
    const ushort_t* __restrict__ v, ushort_t* __restrict__ vt) {
  int bh = blockIdx.y;
  int b = bh >> 4, h = bh & 15;
  int s0 = blockIdx.x * 64;
  __shared__ ushort_t tile[64][65];
  for (int i = threadIdx.x; i < 64 * 64; i += 256) {
    int sl = i >> 6, dl = i & 63;
    tile[dl][sl] = v[((size_t)(b * SEQ + s0 + sl)) * D_MODEL + h * DK + dl];
  }
  __syncthreads();
  for (int i = threadIdx.x; i < 64 * 64; i += 256) {
    int dl = i >> 6, sl = i & 63;
    vt[((size_t)bh * DK + dl) * SEQ + s0 + sl] = tile[dl][sl];
  }
}

// ---------------- flash attention, causal, intra-block split-K ----------------
// grid (128, B*H). Block = one 16-row q-tile (longest-first); 4 waves split the
// key range in 64-key tiles (jt = w, w+4, ...), merged at the end via LDS
// log-sum-exp. Scores computed TRANSPOSED (S^T = K·Q^T): C rows = keys,
// C cols = queries, so the softmax key-reduction is 15 in-register VALU ops +
// 2 shuffles (xor16, xor32) instead of 4 rows x 4 butterfly steps.
// Per-query state (m_i, l_i, alpha) lives once per lane (query = col).
struct WaveMem {
  union {
    struct {
      ushort_t pbuf[16][72];   // [query][key], stride 72: 8B/16B-aligned, conflict-light
      float abuf[16];          // alpha per query, broadcast to o-rows
    } s;
    float obuf[4][64][4];      // merge phase: [c2][lane][r]
  };
};

__global__ __launch_bounds__(256) void attn_kernel(
    const ushort_t* __restrict__ q, const ushort_t* __restrict__ k,
    const ushort_t* __restrict__ vt, ushort_t* __restrict__ out) {
  const int bh = blockIdx.y;
  const int b = bh >> 4, h = bh & 15;
  const int w = threadIdx.x >> 6, lane = threadIdx.x & 63;
  const int col = lane & 15, quad = lane >> 4;
  const int t = 127 - blockIdx.x;        // longest-first for tail balance
  const int s0 = t * 16;

  const size_t base = ((size_t)(b * SEQ)) * D_MODEL + h * DK;
  short8 qf[2];
#pragma unroll
  for (int kk = 0; kk < 2; kk++)
    qf[kk] = *(const short8*)&q[base + (size_t)(s0 + col) * D_MODEL + kk * 32 + quad * 8];

  f32x4 o[4] = {};
  float m_i = -__builtin_inff();   // running max for query s0+col
  float l_i = 0.f;

  __shared__ __align__(16) WaveMem wmem[4];
  __shared__ float mbuf[4][16];
  __shared__ float lbuf[4][16];
  WaveMem& wm = wmem[w];

  const int ntiles = (s0 + 16 + 63) >> 6;   // 64-key tiles covering [0, s0+16)
  for (int jt = w; jt < ntiles; jt += 4) {
    const int skey = jt * 64;
    // S^T[key][query]: A = K rows (keys), B = Q rows (queries)
    f32x4 S[4] = {};
#pragma unroll
    for (int kk = 0; kk < 2; kk++) {
#pragma unroll
      for (int sub = 0; sub < 4; sub++) {
        short8 kf = *(const short8*)&k[base + (size_t)(skey + sub * 16 + col) * D_MODEL + kk * 32 + quad * 8];
        S[sub] = __builtin_amdgcn_mfma_f32_16x16x32_bf16(kf, qf[kk], S[sub], 0, 0, 0);
      }
    }
    // lane holds S^T[key = skey + sub*16 + quad*4 + r][query = s0 + col]
    float sv[4][4];
#pragma unroll
    for (int sub = 0; sub < 4; sub++)
#pragma unroll
      for (int r = 0; r < 4; r++) sv[sub][r] = S[sub][r] * 0.125f;
    if (skey + 63 > s0) {   // diagonal tile: causal mask (key > query -> -inf)
      const int kb = skey + quad * 4 - s0 - col;   // + sub*16 + r > 0 means masked
#pragma unroll
      for (int sub = 0; sub < 4; sub++)
#pragma unroll
        for (int r = 0; r < 4; r++)
          if (kb + sub * 16 + r > 0) sv[sub][r] = -__builtin_inff();
    }
    // column (per-query) max: 15 VALU + 2 shuffles
    float mt = sv[0][0];
#pragma unroll
    for (int sub = 0; sub < 4; sub++)
#pragma unroll
      for (int r = 0; r < 4; r++) mt = fmaxf(mt, sv[sub][r]);
    mt = fmaxf(mt, __shfl_xor(mt, 16));
    mt = fmaxf(mt, __shfl_xor(mt, 32));
    const float mn = fmaxf(m_i, mt);
    const float alpha = __expf(m_i - mn);
    m_i = mn;
    float p[4][4];
    float ps = 0.f;
#pragma unroll
    for (int sub = 0; sub < 4; sub++)
#pragma unroll
      for (int r = 0; r < 4; r++) { p[sub][r] = __expf(sv[sub][r] - mn); ps += p[sub][r]; }
    ps += __shfl_xor(ps, 16);
    ps += __shfl_xor(ps, 32);
    l_i = alpha * l_i + ps;
    // write P transposed into [query][key] layout: one 8B write per sub-tile
#pragma unroll
    for (int sub = 0; sub < 4; sub++) {
      ushort4 pk;
      pk.x = f2bf(p[sub][0]); pk.y = f2bf(p[sub][1]);
      pk.z = f2bf(p[sub][2]); pk.w = f2bf(p[sub][3]);
      *(ushort4*)&wm.s.pbuf[col][sub * 16 + quad * 4] = pk;
    }
    if (quad == 0) wm.s.abuf[col] = alpha;
    __builtin_amdgcn_s_waitcnt(0xC07F);   // lgkmcnt(0): own-wave LDS visible
    const f32x4 av = *(const f32x4*)&wm.s.abuf[quad * 4];   // alpha for query quad*4+r
    const short8 pf0 = *(const short8*)&wm.s.pbuf[col][quad * 8];        // keys 0..31
    const short8 pf1 = *(const short8*)&wm.s.pbuf[col][32 + quad * 8];   // keys 32..63
#pragma unroll
    for (int c2 = 0; c2 < 4; c2++) {
#pragma unroll
      for (int r = 0; r < 4; r++) o[c2][r] *= av[r];
      const ushort_t* vrow = &vt[((size_t)bh * DK + c2 * 16 + col) * SEQ + skey];
      short8 vf0 = *(const short8*)&vrow[quad * 8];
      short8 vf1 = *(const short8*)&vrow[32 + quad * 8];
      o[c2] = __builtin_amdgcn_mfma_f32_16x16x32_bf16(pf0, vf0, o[c2], 0, 0, 0);
      o[c2] = __builtin_amdgcn_mfma_f32_16x16x32_bf16(pf1, vf1, o[c2], 0, 0, 0);
    }
  }

  // ---- merge partials across the 4 waves ----
  if (quad == 0) { mbuf[w][col] = m_i; lbuf[w][col] = l_i; }
  __syncthreads();   // all waves done with pbuf before obuf aliasing is read
#pragma unroll
  for (int c2 = 0; c2 < 4; c2++)
    *(f32x4*)&wm.obuf[c2][lane][0] = o[c2];
  __syncthreads();

  float M[4], L[4], sc[4][4];   // sc[src wave][r]
#pragma unroll
  for (int r = 0; r < 4; r++) {
    int row = quad * 4 + r;
    float m0 = mbuf[0][row], m1 = mbuf[1][row], m2 = mbuf[2][row], m3 = mbuf[3][row];
    M[r] = fmaxf(fmaxf(m0, m1), fmaxf(m2, m3));
    float e0 = __expf(m0 - M[r]);
    float e1 = __expf(m1 - M[r]);
    float e2 = __expf(m2 - M[r]);
    float e3 = __expf(m3 - M[r]);
    sc[0][r] = e0; sc[1][r] = e1; sc[2][r] = e2; sc[3][r] = e3;
    L[r] = lbuf[0][row] * e0 + lbuf[1][row] * e1 + lbuf[2][row] * e2 + lbuf[3][row] * e3;
  }
  f32x4 oo = {};
#pragma unroll
  for (int wp = 0; wp < 4; wp++) {
    f32x4 tv = *(const f32x4*)&wmem[wp].obuf[w][lane][0];
#pragma unroll
    for (int r = 0; r < 4; r++) oo[r] += tv[r] * sc[wp][r];
  }
#pragma unroll
  for (int r = 0; r < 4; r++) {
    int row = s0 + quad * 4 + r;
    out[((size_t)(b * SEQ) + row) * D_MODEL + h * DK + w * 16 + col] = f2bf(oo[r] / L[r]);
  }
}

// ---------------- SwiGLU elementwise: u = silu(u)*g ----------------
__global__ __launch_bounds__(256) void silu_mul_kernel(
    ushort_t* __restrict__ u, const ushort_t* __restrict__ g, int n8) {
  int i = blockIdx.x * 256 + threadIdx.x;
  if (i >= n8) return;
  short8 uv = ((const short8*)u)[i];
  short8 gv = ((const short8*)g)[i];
  short8 t;
#pragma unroll
  for (int j = 0; j < 8; j++) {
    float x = bf2f((ushort_t)uv[j]);
    float gg = bf2f((ushort_t)gv[j]);
    float s = x / (1.f + __expf(-x));
    t[j] = (short)f2bf(s * gg);
  }
  ((short8*)u)[i] = t;
}

// ---------------- launcher ----------------
extern "C" void kernel_launch(void* const* d_in, const int* in_sizes, int n_in,
                              void* d_out, int out_size, void* d_ws, size_t ws_size,
                              hipStream_t stream) {
  const float* x  = (const float*)d_in[0];
  const float* g1 = (const float*)d_in[1];
  const float* g2 = (const float*)d_in[2];
  const float* WQ = (const float*)d_in[3];
  const float* WK = (const float*)d_in[4];
  const float* WV = (const float*)d_in[5];
  const float* WO = (const float*)d_in[6];
  const float* W1 = (const float*)d_in[7];
  const float* W2 = (const float*)d_in[8];
  const float* W3 = (const float*)d_in[9];
  float* out = (float*)d_out;

  char* p = (char*)d_ws;
  auto alloc = [&](size_t bytes) {
    char* r = p; p += (bytes + 255) & ~(size_t)255; return r;
  };
  ushort_t* wq  = (ushort_t*)alloc((size_t)D_MODEL * D_MODEL * 2);
  ushort_t* wk  = (ushort_t*)alloc((size_t)D_MODEL * D_MODEL * 2);
  ushort_t* wv  = (ushort_t*)alloc((size_t)D_MODEL * D_MODEL * 2);
  ushort_t* wo  = (ushort_t*)alloc((size_t)D_MODEL * D_MODEL * 2);
  ushort_t* w1b = (ushort_t*)alloc((size_t)D_FF * D_MODEL * 2);
  ushort_t* w2b = (ushort_t*)alloc((size_t)D_FF * D_MODEL * 2);
  ushort_t* w3b = (ushort_t*)alloc((size_t)D_FF * D_MODEL * 2);
  ushort_t* h   = (ushort_t*)alloc((size_t)NTOK * D_MODEL * 2);   // also h2
  ushort_t* qb  = (ushort_t*)alloc((size_t)NTOK * D_MODEL * 2);
  ushort_t* kb  = (ushort_t*)alloc((size_t)NTOK * D_MODEL * 2);
  ushort_t* vb  = (ushort_t*)alloc((size_t)NTOK * D_MODEL * 2);   // later reused as attn out
  ushort_t* vtb = (ushort_t*)alloc((size_t)NTOK * D_MODEL * 2);
  float*    y   = (float*)   alloc((size_t)NTOK * D_MODEL * 4);
  ushort_t* ub  = (ushort_t*)alloc((size_t)NTOK * D_FF * 2);      // silu*g in place
  ushort_t* gb  = (ushort_t*)alloc((size_t)NTOK * D_FF * 2);

  const int n4_dd  = D_MODEL * D_MODEL / 4;   // 262144
  const int n4_fd  = D_FF * D_MODEL / 4;      // 720896
  convert_f32_bf16<<<n4_dd / 256, 256, 0, stream>>>(WQ, wq, n4_dd);
  convert_f32_bf16<<<n4_dd / 256, 256, 0, stream>>>(WK, wk, n4_dd);
  convert_f32_bf16<<<n4_dd / 256, 256, 0, stream>>>(WV, wv, n4_dd);
  convert_f32_bf16<<<n4_dd / 256, 256, 0, stream>>>(WO, wo, n4_dd);
  convert_f32_bf16<<<n4_fd / 256, 256, 0, stream>>>(W1, w1b, n4_fd);
  convert_f32_bf16<<<n4_fd / 256, 256, 0, stream>>>(W2, w2b, n4_fd);
  convert_f32_bf16<<<n4_fd / 256, 256, 0, stream>>>(W3, w3b, n4_fd);

  rmsnorm_kernel<<<NTOK, 256, 0, stream>>>(x, g1, h);

  GemmArgs a1{h, wq, wk, wv, qb, kb, vb, nullptr, NTOK, D_MODEL, D_MODEL};
  gemm128<0><<<dim3(D_MODEL / 128, NTOK / 128, 3), 256, 0, stream>>>(a1);

  rope_kernel<<<(BATCH * SEQ * NHEADS) / 4, 256, 0, stream>>>(qb, kb);
  vtrans_kernel<<<dim3(SEQ / 64, BATCH * NHEADS), 256, 0, stream>>>(vb, vtb);
  attn_kernel<<<dim3(SEQ / 16, BATCH * NHEADS), 256, 0, stream>>>(qb, kb, vtb, vb);

  GemmArgs a2{vb, wo, nullptr, nullptr, y, nullptr, nullptr, x, NTOK, D_MODEL, D_MODEL};
  gemm128<1><<<dim3(D_MODEL / 128, NTOK / 128, 1), 256, 0, stream>>>(a2);

  rmsnorm_kernel<<<NTOK, 256, 0, stream>>>(y, g2, h);

  GemmArgs a3{h, w1b, w3b, nullptr, ub, gb, nullptr, nullptr, NTOK, D_FF, D_MODEL};
  gemm128<0><<<dim3(D_FF / 128, NTOK / 128, 2), 256, 0, stream>>>(a3);

  silu_mul_kernel<<<(NTOK * D_FF / 8) / 256, 256, 0, stream>>>(ub, gb, NTOK * D_FF / 8);

  GemmArgs a4{ub, w2b, nullptr, nullptr, out, nullptr, nullptr, y, NTOK, D_MODEL, D_FF};
  gemm128<1><<<dim3(D_MODEL / 128, NTOK / 128, 1), 256, 0, stream>>>(a4);
}

// Round 4
// 471.629 us; speedup vs baseline: 1.3146x; 1.1683x over previous
//
#include <hip/hip_runtime.h>
#include <cstdint>
#include <cstddef>

typedef short short8 __attribute__((ext_vector_type(8)));
typedef float f32x4 __attribute__((ext_vector_type(4)));
typedef unsigned short ushort_t;

#define D_MODEL 1024
#define D_FF    2816
#define SEQ     2048
#define BATCH   2
#define NHEADS  16
#define DK      64
#define NTOK    (BATCH*SEQ)   // 4096

__device__ __forceinline__ float bf2f(ushort_t u) {
  return __builtin_bit_cast(float, (unsigned int)u << 16);
}
__device__ __forceinline__ ushort_t f2bf(float f) {
  unsigned int x = __builtin_bit_cast(unsigned int, f);
  x += 0x7fffu + ((x >> 16) & 1u);   // round-to-nearest-even
  return (ushort_t)(x >> 16);
}

// async global->LDS, 16B per lane. LDS dest = wave-uniform base + lane*16.
__device__ __forceinline__ void gld16(const ushort_t* g, ushort_t* l) {
  __builtin_amdgcn_global_load_lds(
      (const __attribute__((address_space(1))) unsigned int*)g,
      (__attribute__((address_space(3))) unsigned int*)l,
      16, 0, 0);
}

// ---------------- fp32 -> bf16 convert ----------------
__global__ __launch_bounds__(256) void convert_f32_bf16(
    const float* __restrict__ src, ushort_t* __restrict__ dst, int n4) {
  int i = blockIdx.x * 256 + threadIdx.x;
  if (i >= n4) return;
  float4 v = ((const float4*)src)[i];
  ushort4 o;
  o.x = f2bf(v.x); o.y = f2bf(v.y); o.z = f2bf(v.z); o.w = f2bf(v.w);
  ((ushort4*)dst)[i] = o;
}

// ---------------- RMSNorm (row of 1024) ----------------
__global__ __launch_bounds__(256) void rmsnorm_kernel(
    const float* __restrict__ x, const float* __restrict__ g, ushort_t* __restrict__ out) {
  int row = blockIdx.x;
  int tid = threadIdx.x;
  float4 v = ((const float4*)(x + (size_t)row * D_MODEL))[tid];
  float ss = v.x*v.x + v.y*v.y + v.z*v.z + v.w*v.w;
#pragma unroll
  for (int off = 1; off < 64; off <<= 1) ss += __shfl_xor(ss, off);
  __shared__ float wsum[4];
  if ((tid & 63) == 0) wsum[tid >> 6] = ss;
  __syncthreads();
  float total = wsum[0] + wsum[1] + wsum[2] + wsum[3];
  float rinv = rsqrtf(total * (1.0f / D_MODEL) + 1e-5f);
  float4 gv = ((const float4*)g)[tid];
  ushort4 o;
  o.x = f2bf(v.x * gv.x * rinv);
  o.y = f2bf(v.y * gv.y * rinv);
  o.z = f2bf(v.z * gv.z * rinv);
  o.w = f2bf(v.w * gv.w * rinv);
  ((ushort4*)(out + (size_t)row * D_MODEL))[tid] = o;
}

// ---------------- GEMM: C[M,N] = A[M,K] * B[N,K]^T ----------------
// m97 structure: 128x128 tile, BK=32, 4 waves each 64x64, global_load_lds w=16.
struct GemmArgs {
  const ushort_t* A;
  const ushort_t* B0; const ushort_t* B1; const ushort_t* B2;
  void* C0; void* C1; void* C2;
  const float* resid;   // EPI==1
  int M, N, K;
};

template<int EPI>  // 0: store bf16; 1: store fp32 = acc + resid
__global__ __launch_bounds__(256) void gemm128(GemmArgs args) {
  const ushort_t* B = blockIdx.z == 0 ? args.B0 : (blockIdx.z == 1 ? args.B1 : args.B2);
  void* C = blockIdx.z == 0 ? args.C0 : (blockIdx.z == 1 ? args.C1 : args.C2);
  const int N = args.N, K = args.K;
  __shared__ __align__(16) ushort_t sA[128 * 32];
  __shared__ __align__(16) ushort_t sB[128 * 32];
  const int tid  = threadIdx.x;
  const int w    = tid >> 6;
  const int lane = tid & 63;
  const int col  = lane & 15;
  const int quad = lane >> 4;
  const int waveM = (w >> 1) * 64;
  const int waveN = (w & 1) * 64;
  const int bm = blockIdx.y * 128;
  const int bn = blockIdx.x * 128;

  f32x4 acc[4][4] = {};

  const int srow = tid >> 2;           // 0..63
  const int scol = (tid & 3) * 8;
  const ushort_t* gA = args.A + (size_t)(bm + srow) * K + scol;
  const ushort_t* gB = B      + (size_t)(bn + srow) * K + scol;
  ushort_t* lA = sA + tid * 8;         // byte off = tid*16
  ushort_t* lB = sB + tid * 8;
  const size_t rstep = (size_t)64 * K;

  for (int k0 = 0; k0 < K; k0 += 32) {
    gld16(gA + k0,         lA);
    gld16(gA + k0 + rstep, lA + 2048);   // rows 64..127 -> +4096 B
    gld16(gB + k0,         lB);
    gld16(gB + k0 + rstep, lB + 2048);
    __syncthreads();                     // drains vmcnt -> LDS ready
    short8 af[4], bf[4];
#pragma unroll
    for (int mi = 0; mi < 4; mi++)
      af[mi] = *(const short8*)&sA[(waveM + mi * 16 + col) * 32 + quad * 8];
#pragma unroll
    for (int ni = 0; ni < 4; ni++)
      bf[ni] = *(const short8*)&sB[(waveN + ni * 16 + col) * 32 + quad * 8];
#pragma unroll
    for (int mi = 0; mi < 4; mi++)
#pragma unroll
      for (int ni = 0; ni < 4; ni++)
        acc[mi][ni] = __builtin_amdgcn_mfma_f32_16x16x32_bf16(af[mi], bf[ni], acc[mi][ni], 0, 0, 0);
    __syncthreads();                     // all reads done before next stage
  }

#pragma unroll
  for (int mi = 0; mi < 4; mi++) {
    int r0 = bm + waveM + mi * 16 + quad * 4;
#pragma unroll
    for (int ni = 0; ni < 4; ni++) {
      int c0 = bn + waveN + ni * 16 + col;
#pragma unroll
      for (int r = 0; r < 4; r++) {
        size_t idx = (size_t)(r0 + r) * N + c0;
        if (EPI == 0) ((ushort_t*)C)[idx] = f2bf(acc[mi][ni][r]);
        else          ((float*)C)[idx]    = acc[mi][ni][r] + args.resid[idx];
      }
    }
  }
}

// ---------------- RoPE (q,k in place), one wave per (b,s,h) ----------------
__global__ __launch_bounds__(256) void rope_kernel(
    ushort_t* __restrict__ q, ushort_t* __restrict__ k) {
  int item = blockIdx.x * 4 + (threadIdx.x >> 6);   // 0..65535
  int lane = threadIdx.x & 63;
  int h = item & 15;
  int s = (item >> 4) & (SEQ - 1);
  int b = item >> 15;
  size_t idx = ((size_t)(b * SEQ + s)) * D_MODEL + h * DK + lane;
  int p = lane >> 1;
  // inv = 10000^(-2p/64) = exp(-(p/32)*ln(10000))
  float inv = expf(-(float)p * (9.210340372f / 32.0f));
  float ang = (float)s * inv;
  float cs = cosf(ang), sn = sinf(ang);
  float qv = bf2f(q[idx]);
  float kv = bf2f(k[idx]);
  float qp = __shfl_xor(qv, 1);
  float kp = __shfl_xor(kv, 1);
  float sgn = (lane & 1) ? sn : -sn;   // even: x*c - x1*s ; odd: x*c + x0*s
  q[idx] = f2bf(qv * cs + qp * sgn);
  k[idx] = f2bf(kv * cs + kp * sgn);
}

// ---------------- V transpose: [B,S,H*dk] -> [B,H,dk,S] ----------------
__global__ __launch_bounds__(256) void vtrans_kernel(
    const ushort_t* __restrict__ v, ushort_t* __restrict__ vt) {
  int bh = blockIdx.y;
  int b = bh >> 4, h = bh & 15;
  int s0 = blockIdx.x * 64;
  __shared__ ushort_t tile[64][65];
  for (int i = threadIdx.x; i < 64 * 64; i += 256) {
    int sl = i >> 6, dl = i & 63;
    tile[dl][sl] = v[((size_t)(b * SEQ + s0 + sl)) * D_MODEL + h * DK + dl];
  }
  __syncthreads();
  for (int i = threadIdx.x; i < 64 * 64; i += 256) {
    int dl = i >> 6, sl = i & 63;
    vt[((size_t)bh * DK + dl) * SEQ + s0 + sl] = tile[dl][sl];
  }
}

// ---------------- flash attention, causal, q-tile 32, XCD-swizzled ----------------
// grid 2048 (1D). bh = blockIdx & 31 so all blocks of one head land on one XCD
// (blockIdx%8 -> XCD round-robin heuristic): K+V per head = 512 KB, 4 heads/XCD
// = 2 MB, resident in the 4 MB per-XCD L2. Block = 32 q-rows (2 q-halves per
// wave, K/V fragments reused for both); 4 waves split keys in 64-key tiles;
// merged via LDS log-sum-exp. Scores transposed (S^T = K*Q^T): softmax
// key-reduction = in-register VALU + 2 shuffles.
struct WaveMem {
  union {
    struct {
      ushort_t pbuf[32][72];   // [query][key], stride 72 (144 B): 16B-aligned reads
      float abuf[32];          // alpha per query
    } s;
    float obuf[2][4][64][4];   // merge: [qh][c2][lane][r]
  };
};

__global__ __launch_bounds__(256) void attn_kernel(
    const ushort_t* __restrict__ q, const ushort_t* __restrict__ k,
    const ushort_t* __restrict__ vt, ushort_t* __restrict__ out) {
  const int bidx = blockIdx.x;
  const int bh = bidx & 31;              // head -> XCD affinity via %8
  const int b = bh >> 4, h = bh & 15;
  const int t = 63 - (bidx >> 5);        // longest-first
  const int s0 = t * 32;
  const int w = threadIdx.x >> 6, lane = threadIdx.x & 63;
  const int col = lane & 15, quad = lane >> 4;
  const size_t base = ((size_t)(b * SEQ)) * D_MODEL + h * DK;

  short8 qf[2][2];   // [qh][kk]
#pragma unroll
  for (int qh = 0; qh < 2; qh++)
#pragma unroll
    for (int kk = 0; kk < 2; kk++)
      qf[qh][kk] = *(const short8*)&q[base + (size_t)(s0 + qh * 16 + col) * D_MODEL + kk * 32 + quad * 8];

  f32x4 o[2][4] = {};
  float m_i[2] = {-__builtin_inff(), -__builtin_inff()};
  float l_i[2] = {0.f, 0.f};

  __shared__ __align__(16) WaveMem wmem[4];
  __shared__ float mbuf[4][32];
  __shared__ float lbuf[4][32];
  WaveMem& wm = wmem[w];

  const int ntiles = (s0 + 32 + 63) >> 6;
  for (int jt = w; jt < ntiles; jt += 4) {
    const int skey = jt * 64;
    f32x4 S[2][4] = {};
#pragma unroll
    for (int kk = 0; kk < 2; kk++) {
#pragma unroll
      for (int sub = 0; sub < 4; sub++) {
        short8 kf = *(const short8*)&k[base + (size_t)(skey + sub * 16 + col) * D_MODEL + kk * 32 + quad * 8];
        S[0][sub] = __builtin_amdgcn_mfma_f32_16x16x32_bf16(kf, qf[0][kk], S[0][sub], 0, 0, 0);
        S[1][sub] = __builtin_amdgcn_mfma_f32_16x16x32_bf16(kf, qf[1][kk], S[1][sub], 0, 0, 0);
      }
    }
    // lane holds S^T[key = skey+sub*16+quad*4+r][query = s0+qh*16+col]
    float sv[2][4][4];
#pragma unroll
    for (int qh = 0; qh < 2; qh++)
#pragma unroll
      for (int sub = 0; sub < 4; sub++)
#pragma unroll
        for (int r = 0; r < 4; r++) sv[qh][sub][r] = S[qh][sub][r] * 0.125f;
    if (skey + 63 > s0) {   // causal mask: key > query -> -inf
#pragma unroll
      for (int qh = 0; qh < 2; qh++) {
        const int kb = skey + quad * 4 - s0 - qh * 16 - col;
#pragma unroll
        for (int sub = 0; sub < 4; sub++)
#pragma unroll
          for (int r = 0; r < 4; r++)
            if (kb + sub * 16 + r > 0) sv[qh][sub][r] = -__builtin_inff();
      }
    }
#pragma unroll
    for (int qh = 0; qh < 2; qh++) {
      float mt = sv[qh][0][0];
#pragma unroll
      for (int sub = 0; sub < 4; sub++)
#pragma unroll
        for (int r = 0; r < 4; r++) mt = fmaxf(mt, sv[qh][sub][r]);
      mt = fmaxf(mt, __shfl_xor(mt, 16));
      mt = fmaxf(mt, __shfl_xor(mt, 32));
      const float mn = fmaxf(m_i[qh], mt);
      const float alpha = __expf(m_i[qh] - mn);
      m_i[qh] = mn;
      float p[4][4];
      float ps = 0.f;
#pragma unroll
      for (int sub = 0; sub < 4; sub++)
#pragma unroll
        for (int r = 0; r < 4; r++) { p[sub][r] = __expf(sv[qh][sub][r] - mn); ps += p[sub][r]; }
      ps += __shfl_xor(ps, 16);
      ps += __shfl_xor(ps, 32);
      l_i[qh] = alpha * l_i[qh] + ps;
#pragma unroll
      for (int sub = 0; sub < 4; sub++) {
        ushort4 pk;
        pk.x = f2bf(p[sub][0]); pk.y = f2bf(p[sub][1]);
        pk.z = f2bf(p[sub][2]); pk.w = f2bf(p[sub][3]);
        *(ushort4*)&wm.s.pbuf[qh * 16 + col][sub * 16 + quad * 4] = pk;
      }
      if (quad == 0) wm.s.abuf[qh * 16 + col] = alpha;
    }
    __builtin_amdgcn_s_waitcnt(0xC07F);   // lgkmcnt(0): own-wave LDS visible
    const f32x4 av0 = *(const f32x4*)&wm.s.abuf[quad * 4];
    const f32x4 av1 = *(const f32x4*)&wm.s.abuf[16 + quad * 4];
    short8 pf[2][2];
#pragma unroll
    for (int qh = 0; qh < 2; qh++) {
      pf[qh][0] = *(const short8*)&wm.s.pbuf[qh * 16 + col][quad * 8];
      pf[qh][1] = *(const short8*)&wm.s.pbuf[qh * 16 + col][32 + quad * 8];
    }
#pragma unroll
    for (int c2 = 0; c2 < 4; c2++) {
      const ushort_t* vrow = &vt[((size_t)bh * DK + c2 * 16 + col) * SEQ + skey];
      short8 vf0 = *(const short8*)&vrow[quad * 8];
      short8 vf1 = *(const short8*)&vrow[32 + quad * 8];
#pragma unroll
      for (int r = 0; r < 4; r++) { o[0][c2][r] *= av0[r]; o[1][c2][r] *= av1[r]; }
      o[0][c2] = __builtin_amdgcn_mfma_f32_16x16x32_bf16(pf[0][0], vf0, o[0][c2], 0, 0, 0);
      o[0][c2] = __builtin_amdgcn_mfma_f32_16x16x32_bf16(pf[0][1], vf1, o[0][c2], 0, 0, 0);
      o[1][c2] = __builtin_amdgcn_mfma_f32_16x16x32_bf16(pf[1][0], vf0, o[1][c2], 0, 0, 0);
      o[1][c2] = __builtin_amdgcn_mfma_f32_16x16x32_bf16(pf[1][1], vf1, o[1][c2], 0, 0, 0);
    }
  }

  // ---- merge partials across the 4 waves ----
#pragma unroll
  for (int qh = 0; qh < 2; qh++)
#pragma unroll
    for (int c2 = 0; c2 < 4; c2++)
      *(f32x4*)&wm.obuf[qh][c2][lane][0] = o[qh][c2];
  if (quad == 0) {
    mbuf[w][col]      = m_i[0];  mbuf[w][16 + col] = m_i[1];
    lbuf[w][col]      = l_i[0];  lbuf[w][16 + col] = l_i[1];
  }
  __syncthreads();

#pragma unroll
  for (int qh = 0; qh < 2; qh++) {
    float M[4], L[4], sc[4][4];
#pragma unroll
    for (int r = 0; r < 4; r++) {
      int row = qh * 16 + quad * 4 + r;
      float m0 = mbuf[0][row], m1 = mbuf[1][row], m2 = mbuf[2][row], m3 = mbuf[3][row];
      M[r] = fmaxf(fmaxf(m0, m1), fmaxf(m2, m3));
      float e0 = __expf(m0 - M[r]);
      float e1 = __expf(m1 - M[r]);
      float e2 = __expf(m2 - M[r]);
      float e3 = __expf(m3 - M[r]);
      sc[0][r] = e0; sc[1][r] = e1; sc[2][r] = e2; sc[3][r] = e3;
      L[r] = lbuf[0][row] * e0 + lbuf[1][row] * e1 + lbuf[2][row] * e2 + lbuf[3][row] * e3;
    }
    f32x4 oo = {};
#pragma unroll
    for (int wp = 0; wp < 4; wp++) {
      f32x4 tv = *(const f32x4*)&wmem[wp].obuf[qh][w][lane][0];
#pragma unroll
      for (int r = 0; r < 4; r++) oo[r] += tv[r] * sc[wp][r];
    }
#pragma unroll
    for (int r = 0; r < 4; r++) {
      int row = s0 + qh * 16 + quad * 4 + r;
      out[((size_t)(b * SEQ) + row) * D_MODEL + h * DK + w * 16 + col] = f2bf(oo[r] / L[r]);
    }
  }
}

// ---------------- SwiGLU elementwise: u = silu(u)*g ----------------
__global__ __launch_bounds__(256) void silu_mul_kernel(
    ushort_t* __restrict__ u, const ushort_t* __restrict__ g, int n8) {
  int i = blockIdx.x * 256 + threadIdx.x;
  if (i >= n8) return;
  short8 uv = ((const short8*)u)[i];
  short8 gv = ((const short8*)g)[i];
  short8 t;
#pragma unroll
  for (int j = 0; j < 8; j++) {
    float x = bf2f((ushort_t)uv[j]);
    float gg = bf2f((ushort_t)gv[j]);
    float s = x / (1.f + __expf(-x));
    t[j] = (short)f2bf(s * gg);
  }
  ((short8*)u)[i] = t;
}

// ---------------- launcher ----------------
extern "C" void kernel_launch(void* const* d_in, const int* in_sizes, int n_in,
                              void* d_out, int out_size, void* d_ws, size_t ws_size,
                              hipStream_t stream) {
  const float* x  = (const float*)d_in[0];
  const float* g1 = (const float*)d_in[1];
  const float* g2 = (const float*)d_in[2];
  const float* WQ = (const float*)d_in[3];
  const float* WK = (const float*)d_in[4];
  const float* WV = (const float*)d_in[5];
  const float* WO = (const float*)d_in[6];
  const float* W1 = (const float*)d_in[7];
  const float* W2 = (const float*)d_in[8];
  const float* W3 = (const float*)d_in[9];
  float* out = (float*)d_out;

  char* p = (char*)d_ws;
  auto alloc = [&](size_t bytes) {
    char* r = p; p += (bytes + 255) & ~(size_t)255; return r;
  };
  ushort_t* wq  = (ushort_t*)alloc((size_t)D_MODEL * D_MODEL * 2);
  ushort_t* wk  = (ushort_t*)alloc((size_t)D_MODEL * D_MODEL * 2);
  ushort_t* wv  = (ushort_t*)alloc((size_t)D_MODEL * D_MODEL * 2);
  ushort_t* wo  = (ushort_t*)alloc((size_t)D_MODEL * D_MODEL * 2);
  ushort_t* w1b = (ushort_t*)alloc((size_t)D_FF * D_MODEL * 2);
  ushort_t* w2b = (ushort_t*)alloc((size_t)D_FF * D_MODEL * 2);
  ushort_t* w3b = (ushort_t*)alloc((size_t)D_FF * D_MODEL * 2);
  ushort_t* h   = (ushort_t*)alloc((size_t)NTOK * D_MODEL * 2);   // also h2
  ushort_t* qb  = (ushort_t*)alloc((size_t)NTOK * D_MODEL * 2);
  ushort_t* kb  = (ushort_t*)alloc((size_t)NTOK * D_MODEL * 2);
  ushort_t* vb  = (ushort_t*)alloc((size_t)NTOK * D_MODEL * 2);   // later reused as attn out
  ushort_t* vtb = (ushort_t*)alloc((size_t)NTOK * D_MODEL * 2);
  float*    y   = (float*)   alloc((size_t)NTOK * D_MODEL * 4);
  ushort_t* ub  = (ushort_t*)alloc((size_t)NTOK * D_FF * 2);      // silu*g in place
  ushort_t* gb  = (ushort_t*)alloc((size_t)NTOK * D_FF * 2);

  const int n4_dd  = D_MODEL * D_MODEL / 4;   // 262144
  const int n4_fd  = D_FF * D_MODEL / 4;      // 720896
  convert_f32_bf16<<<n4_dd / 256, 256, 0, stream>>>(WQ, wq, n4_dd);
  convert_f32_bf16<<<n4_dd / 256, 256, 0, stream>>>(WK, wk, n4_dd);
  convert_f32_bf16<<<n4_dd / 256, 256, 0, stream>>>(WV, wv, n4_dd);
  convert_f32_bf16<<<n4_dd / 256, 256, 0, stream>>>(WO, wo, n4_dd);
  convert_f32_bf16<<<n4_fd / 256, 256, 0, stream>>>(W1, w1b, n4_fd);
  convert_f32_bf16<<<n4_fd / 256, 256, 0, stream>>>(W2, w2b, n4_fd);
  convert_f32_bf16<<<n4_fd / 256, 256, 0, stream>>>(W3, w3b, n4_fd);

  rmsnorm_kernel<<<NTOK, 256, 0, stream>>>(x, g1, h);

  GemmArgs a1{h, wq, wk, wv, qb, kb, vb, nullptr, NTOK, D_MODEL, D_MODEL};
  gemm128<0><<<dim3(D_MODEL / 128, NTOK / 128, 3), 256, 0, stream>>>(a1);

  rope_kernel<<<(BATCH * SEQ * NHEADS) / 4, 256, 0, stream>>>(qb, kb);
  vtrans_kernel<<<dim3(SEQ / 64, BATCH * NHEADS), 256, 0, stream>>>(vb, vtb);
  attn_kernel<<<dim3((SEQ / 32) * 32, 1), 256, 0, stream>>>(qb, kb, vtb, vb);

  GemmArgs a2{vb, wo, nullptr, nullptr, y, nullptr, nullptr, x, NTOK, D_MODEL, D_MODEL};
  gemm128<1><<<dim3(D_MODEL / 128, NTOK / 128, 1), 256, 0, stream>>>(a2);

  rmsnorm_kernel<<<NTOK, 256, 0, stream>>>(y, g2, h);

  GemmArgs a3{h, w1b, w3b, nullptr, ub, gb, nullptr, nullptr, NTOK, D_FF, D_MODEL};
  gemm128<0><<<dim3(D_FF / 128, NTOK / 128, 2), 256, 0, stream>>>(a3);

  silu_mul_kernel<<<(NTOK * D_FF / 8) / 256, 256, 0, stream>>>(ub, gb, NTOK * D_FF / 8);

  GemmArgs a4{ub, w2b, nullptr, nullptr, out, nullptr, nullptr, y, NTOK, D_MODEL, D_FF};
  gemm128<1><<<dim3(D_MODEL / 128, NTOK / 128, 1), 256, 0, stream>>>(a4);
}

// Round 5
// 441.386 us; speedup vs baseline: 1.4046x; 1.0685x over previous
//
#include <hip/hip_runtime.h>
#include <cstdint>
#include <cstddef>

typedef short short8 __attribute__((ext_vector_type(8)));
typedef float f32x4 __attribute__((ext_vector_type(4)));
typedef unsigned short ushort_t;

#define D_MODEL 1024
#define D_FF    2816
#define SEQ     2048
#define BATCH   2
#define NHEADS  16
#define DK      64
#define NTOK    (BATCH*SEQ)   // 4096

__device__ __forceinline__ float bf2f(ushort_t u) {
  return __builtin_bit_cast(float, (unsigned int)u << 16);
}
__device__ __forceinline__ ushort_t f2bf(float f) {
  unsigned int x = __builtin_bit_cast(unsigned int, f);
  x += 0x7fffu + ((x >> 16) & 1u);   // round-to-nearest-even
  return (ushort_t)(x >> 16);
}

// async global->LDS, 16B per lane. LDS dest = wave-uniform base + lane*16.
__device__ __forceinline__ void gld16(const ushort_t* g, ushort_t* l) {
  __builtin_amdgcn_global_load_lds(
      (const __attribute__((address_space(1))) unsigned int*)g,
      (__attribute__((address_space(3))) unsigned int*)l,
      16, 0, 0);
}

// ---------------- fp32 -> bf16 convert, all 7 weights in one launch ----------------
struct CvtArgs {
  const float* src[7];
  ushort_t* dst[7];
  int nblk[7];   // blocks per segment (n4/256)
};
__global__ __launch_bounds__(256) void convert_all(CvtArgs a) {
  int off = blockIdx.x;
  int seg = 0;
  while (off >= a.nblk[seg]) { off -= a.nblk[seg]; seg++; }   // wave-uniform
  int i = off * 256 + threadIdx.x;
  float4 v = ((const float4*)a.src[seg])[i];
  ushort4 o;
  o.x = f2bf(v.x); o.y = f2bf(v.y); o.z = f2bf(v.z); o.w = f2bf(v.w);
  ((ushort4*)a.dst[seg])[i] = o;
}

// ---------------- RMSNorm (row of 1024) ----------------
__global__ __launch_bounds__(256) void rmsnorm_kernel(
    const float* __restrict__ x, const float* __restrict__ g, ushort_t* __restrict__ out) {
  int row = blockIdx.x;
  int tid = threadIdx.x;
  float4 v = ((const float4*)(x + (size_t)row * D_MODEL))[tid];
  float ss = v.x*v.x + v.y*v.y + v.z*v.z + v.w*v.w;
#pragma unroll
  for (int off = 1; off < 64; off <<= 1) ss += __shfl_xor(ss, off);
  __shared__ float wsum[4];
  if ((tid & 63) == 0) wsum[tid >> 6] = ss;
  __syncthreads();
  float total = wsum[0] + wsum[1] + wsum[2] + wsum[3];
  float rinv = rsqrtf(total * (1.0f / D_MODEL) + 1e-5f);
  float4 gv = ((const float4*)g)[tid];
  ushort4 o;
  o.x = f2bf(v.x * gv.x * rinv);
  o.y = f2bf(v.y * gv.y * rinv);
  o.z = f2bf(v.z * gv.z * rinv);
  o.w = f2bf(v.w * gv.w * rinv);
  ((ushort4*)(out + (size_t)row * D_MODEL))[tid] = o;
}

// ---- y = sum(4 partials) + x; h = rmsnorm(y)*g  (fused WO split-K reduce) ----
__global__ __launch_bounds__(256) void rmsnorm_reduce4(
    const float* __restrict__ part, const float* __restrict__ x,
    const float* __restrict__ g, float* __restrict__ y, ushort_t* __restrict__ h) {
  const int row = blockIdx.x;
  const int tid = threadIdx.x;
  const size_t i = (size_t)row * 256 + tid;           // float4 index
  const size_t MN4 = (size_t)NTOK * (D_MODEL / 4);
  float4 v = ((const float4*)x)[i];
#pragma unroll
  for (int jp = 0; jp < 4; jp++) {
    float4 pv = ((const float4*)part)[jp * MN4 + i];
    v.x += pv.x; v.y += pv.y; v.z += pv.z; v.w += pv.w;
  }
  ((float4*)y)[i] = v;
  float ss = v.x*v.x + v.y*v.y + v.z*v.z + v.w*v.w;
#pragma unroll
  for (int off = 1; off < 64; off <<= 1) ss += __shfl_xor(ss, off);
  __shared__ float wsum[4];
  if ((tid & 63) == 0) wsum[tid >> 6] = ss;
  __syncthreads();
  float total = wsum[0] + wsum[1] + wsum[2] + wsum[3];
  float rinv = rsqrtf(total * (1.0f / D_MODEL) + 1e-5f);
  float4 gv = ((const float4*)g)[tid];
  ushort4 o;
  o.x = f2bf(v.x * gv.x * rinv);
  o.y = f2bf(v.y * gv.y * rinv);
  o.z = f2bf(v.z * gv.z * rinv);
  o.w = f2bf(v.w * gv.w * rinv);
  ((ushort4*)(h + (size_t)row * D_MODEL))[tid] = o;
}

// ---- out = sum(4 partials) + y  (W2 split-K reduce + final residual) ----
__global__ __launch_bounds__(256) void add_reduce4(
    const float* __restrict__ part, const float* __restrict__ y, float* __restrict__ out) {
  const size_t i = (size_t)blockIdx.x * 256 + threadIdx.x;
  const size_t MN4 = (size_t)NTOK * (D_MODEL / 4);
  float4 v = ((const float4*)y)[i];
#pragma unroll
  for (int jp = 0; jp < 4; jp++) {
    float4 pv = ((const float4*)part)[jp * MN4 + i];
    v.x += pv.x; v.y += pv.y; v.z += pv.z; v.w += pv.w;
  }
  ((float4*)out)[i] = v;
}

// ---------------- GEMM: C[M,N] = A[M,K] * B[N,K]^T ----------------
// m97 structure: 128x128 tile, BK=32, 4 waves each 64x64, global_load_lds w=16.
struct GemmArgs {
  const ushort_t* A;
  const ushort_t* B0; const ushort_t* B1; const ushort_t* B2;
  void* C0; void* C1; void* C2;
  const float* resid;   // EPI==1
  int M, N, K;
};

template<int EPI>  // 0: store bf16; 1: store fp32 = acc + resid
__global__ __launch_bounds__(256) void gemm128(GemmArgs args) {
  const ushort_t* B = blockIdx.z == 0 ? args.B0 : (blockIdx.z == 1 ? args.B1 : args.B2);
  void* C = blockIdx.z == 0 ? args.C0 : (blockIdx.z == 1 ? args.C1 : args.C2);
  const int N = args.N, K = args.K;
  __shared__ __align__(16) ushort_t sA[128 * 32];
  __shared__ __align__(16) ushort_t sB[128 * 32];
  const int tid  = threadIdx.x;
  const int w    = tid >> 6;
  const int lane = tid & 63;
  const int col  = lane & 15;
  const int quad = lane >> 4;
  const int waveM = (w >> 1) * 64;
  const int waveN = (w & 1) * 64;
  const int bm = blockIdx.y * 128;
  const int bn = blockIdx.x * 128;

  f32x4 acc[4][4] = {};

  const int srow = tid >> 2;           // 0..63
  const int scol = (tid & 3) * 8;
  const ushort_t* gA = args.A + (size_t)(bm + srow) * K + scol;
  const ushort_t* gB = B      + (size_t)(bn + srow) * K + scol;
  ushort_t* lA = sA + tid * 8;         // byte off = tid*16
  ushort_t* lB = sB + tid * 8;
  const size_t rstep = (size_t)64 * K;

  for (int k0 = 0; k0 < K; k0 += 32) {
    gld16(gA + k0,         lA);
    gld16(gA + k0 + rstep, lA + 2048);   // rows 64..127 -> +4096 B
    gld16(gB + k0,         lB);
    gld16(gB + k0 + rstep, lB + 2048);
    __syncthreads();                     // drains vmcnt -> LDS ready
    short8 af[4], bf[4];
#pragma unroll
    for (int mi = 0; mi < 4; mi++)
      af[mi] = *(const short8*)&sA[(waveM + mi * 16 + col) * 32 + quad * 8];
#pragma unroll
    for (int ni = 0; ni < 4; ni++)
      bf[ni] = *(const short8*)&sB[(waveN + ni * 16 + col) * 32 + quad * 8];
#pragma unroll
    for (int mi = 0; mi < 4; mi++)
#pragma unroll
      for (int ni = 0; ni < 4; ni++)
        acc[mi][ni] = __builtin_amdgcn_mfma_f32_16x16x32_bf16(af[mi], bf[ni], acc[mi][ni], 0, 0, 0);
    __syncthreads();                     // all reads done before next stage
  }

#pragma unroll
  for (int mi = 0; mi < 4; mi++) {
    int r0 = bm + waveM + mi * 16 + quad * 4;
#pragma unroll
    for (int ni = 0; ni < 4; ni++) {
      int c0 = bn + waveN + ni * 16 + col;
#pragma unroll
      for (int r = 0; r < 4; r++) {
        size_t idx = (size_t)(r0 + r) * N + c0;
        if (EPI == 0) ((ushort_t*)C)[idx] = f2bf(acc[mi][ni][r]);
        else          ((float*)C)[idx]    = acc[mi][ni][r] + args.resid[idx];
      }
    }
  }
}

// ---- split-K variant: grid.z = 4 K-chunks, fp32 partials to C[z][M*N] ----
struct GemmSplitArgs {
  const ushort_t* A; const ushort_t* B;
  float* C;           // 4 x (NTOK*N) fp32 partials
  int N, K, kchunk;   // kchunk = K/4, multiple of 32
};

__global__ __launch_bounds__(256) void gemm128_splitk(GemmSplitArgs args) {
  const int N = args.N, K = args.K;
  const int kbeg = blockIdx.z * args.kchunk;
  const int kend = kbeg + args.kchunk;
  __shared__ __align__(16) ushort_t sA[128 * 32];
  __shared__ __align__(16) ushort_t sB[128 * 32];
  const int tid  = threadIdx.x;
  const int w    = tid >> 6;
  const int lane = tid & 63;
  const int col  = lane & 15;
  const int quad = lane >> 4;
  const int waveM = (w >> 1) * 64;
  const int waveN = (w & 1) * 64;
  const int bm = blockIdx.y * 128;
  const int bn = blockIdx.x * 128;

  f32x4 acc[4][4] = {};

  const int srow = tid >> 2;
  const int scol = (tid & 3) * 8;
  const ushort_t* gA = args.A + (size_t)(bm + srow) * K + scol;
  const ushort_t* gB = args.B + (size_t)(bn + srow) * K + scol;
  ushort_t* lA = sA + tid * 8;
  ushort_t* lB = sB + tid * 8;
  const size_t rstep = (size_t)64 * K;

  for (int k0 = kbeg; k0 < kend; k0 += 32) {
    gld16(gA + k0,         lA);
    gld16(gA + k0 + rstep, lA + 2048);
    gld16(gB + k0,         lB);
    gld16(gB + k0 + rstep, lB + 2048);
    __syncthreads();
    short8 af[4], bf[4];
#pragma unroll
    for (int mi = 0; mi < 4; mi++)
      af[mi] = *(const short8*)&sA[(waveM + mi * 16 + col) * 32 + quad * 8];
#pragma unroll
    for (int ni = 0; ni < 4; ni++)
      bf[ni] = *(const short8*)&sB[(waveN + ni * 16 + col) * 32 + quad * 8];
#pragma unroll
    for (int mi = 0; mi < 4; mi++)
#pragma unroll
      for (int ni = 0; ni < 4; ni++)
        acc[mi][ni] = __builtin_amdgcn_mfma_f32_16x16x32_bf16(af[mi], bf[ni], acc[mi][ni], 0, 0, 0);
    __syncthreads();
  }

  float* C = args.C + (size_t)blockIdx.z * ((size_t)NTOK * N);
#pragma unroll
  for (int mi = 0; mi < 4; mi++) {
    int r0 = bm + waveM + mi * 16 + quad * 4;
#pragma unroll
    for (int ni = 0; ni < 4; ni++) {
      int c0 = bn + waveN + ni * 16 + col;
#pragma unroll
      for (int r = 0; r < 4; r++)
        C[(size_t)(r0 + r) * N + c0] = acc[mi][ni][r];
    }
  }
}

// ---------------- RoPE (q,k in place), one wave per (b,s,h) ----------------
__global__ __launch_bounds__(256) void rope_kernel(
    ushort_t* __restrict__ q, ushort_t* __restrict__ k) {
  int item = blockIdx.x * 4 + (threadIdx.x >> 6);   // 0..65535
  int lane = threadIdx.x & 63;
  int h = item & 15;
  int s = (item >> 4) & (SEQ - 1);
  int b = item >> 15;
  size_t idx = ((size_t)(b * SEQ + s)) * D_MODEL + h * DK + lane;
  int p = lane >> 1;
  float inv = expf(-(float)p * (9.210340372f / 32.0f));
  float ang = (float)s * inv;
  float cs = cosf(ang), sn = sinf(ang);
  float qv = bf2f(q[idx]);
  float kv = bf2f(k[idx]);
  float qp = __shfl_xor(qv, 1);
  float kp = __shfl_xor(kv, 1);
  float sgn = (lane & 1) ? sn : -sn;
  q[idx] = f2bf(qv * cs + qp * sgn);
  k[idx] = f2bf(kv * cs + kp * sgn);
}

// ---------------- V transpose: [B,S,H*dk] -> [B,H,dk,S] ----------------
__global__ __launch_bounds__(256) void vtrans_kernel(
    const ushort_t* __restrict__ v, ushort_t* __restrict__ vt) {
  int bh = blockIdx.y;
  int b = bh >> 4, h = bh & 15;
  int s0 = blockIdx.x * 64;
  __shared__ ushort_t tile[64][65];
  for (int i = threadIdx.x; i < 64 * 64; i += 256) {
    int sl = i >> 6, dl = i & 63;
    tile[dl][sl] = v[((size_t)(b * SEQ + s0 + sl)) * D_MODEL + h * DK + dl];
  }
  __syncthreads();
  for (int i = threadIdx.x; i < 64 * 64; i += 256) {
    int dl = i >> 6, sl = i & 63;
    vt[((size_t)bh * DK + dl) * SEQ + s0 + sl] = tile[dl][sl];
  }
}

// ---------------- flash attention, causal, q-tile 32, XCD-swizzled ----------------
struct WaveMem {
  union {
    struct {
      ushort_t pbuf[32][72];
      float abuf[32];
    } s;
    float obuf[2][4][64][4];
  };
};

__global__ __launch_bounds__(256) void attn_kernel(
    const ushort_t* __restrict__ q, const ushort_t* __restrict__ k,
    const ushort_t* __restrict__ vt, ushort_t* __restrict__ out) {
  const int bidx = blockIdx.x;
  const int bh = bidx & 31;              // head -> XCD affinity via %8
  const int b = bh >> 4, h = bh & 15;
  const int t = 63 - (bidx >> 5);        // longest-first
  const int s0 = t * 32;
  const int w = threadIdx.x >> 6, lane = threadIdx.x & 63;
  const int col = lane & 15, quad = lane >> 4;
  const size_t base = ((size_t)(b * SEQ)) * D_MODEL + h * DK;

  short8 qf[2][2];
#pragma unroll
  for (int qh = 0; qh < 2; qh++)
#pragma unroll
    for (int kk = 0; kk < 2; kk++)
      qf[qh][kk] = *(const short8*)&q[base + (size_t)(s0 + qh * 16 + col) * D_MODEL + kk * 32 + quad * 8];

  f32x4 o[2][4] = {};
  float m_i[2] = {-__builtin_inff(), -__builtin_inff()};
  float l_i[2] = {0.f, 0.f};

  __shared__ __align__(16) WaveMem wmem[4];
  __shared__ float mbuf[4][32];
  __shared__ float lbuf[4][32];
  WaveMem& wm = wmem[w];

  const int ntiles = (s0 + 32 + 63) >> 6;
  for (int jt = w; jt < ntiles; jt += 4) {
    const int skey = jt * 64;
    f32x4 S[2][4] = {};
#pragma unroll
    for (int kk = 0; kk < 2; kk++) {
#pragma unroll
      for (int sub = 0; sub < 4; sub++) {
        short8 kf = *(const short8*)&k[base + (size_t)(skey + sub * 16 + col) * D_MODEL + kk * 32 + quad * 8];
        S[0][sub] = __builtin_amdgcn_mfma_f32_16x16x32_bf16(kf, qf[0][kk], S[0][sub], 0, 0, 0);
        S[1][sub] = __builtin_amdgcn_mfma_f32_16x16x32_bf16(kf, qf[1][kk], S[1][sub], 0, 0, 0);
      }
    }
    float sv[2][4][4];
#pragma unroll
    for (int qh = 0; qh < 2; qh++)
#pragma unroll
      for (int sub = 0; sub < 4; sub++)
#pragma unroll
        for (int r = 0; r < 4; r++) sv[qh][sub][r] = S[qh][sub][r] * 0.125f;
    if (skey + 63 > s0) {
#pragma unroll
      for (int qh = 0; qh < 2; qh++) {
        const int kb = skey + quad * 4 - s0 - qh * 16 - col;
#pragma unroll
        for (int sub = 0; sub < 4; sub++)
#pragma unroll
          for (int r = 0; r < 4; r++)
            if (kb + sub * 16 + r > 0) sv[qh][sub][r] = -__builtin_inff();
      }
    }
#pragma unroll
    for (int qh = 0; qh < 2; qh++) {
      float mt = sv[qh][0][0];
#pragma unroll
      for (int sub = 0; sub < 4; sub++)
#pragma unroll
        for (int r = 0; r < 4; r++) mt = fmaxf(mt, sv[qh][sub][r]);
      mt = fmaxf(mt, __shfl_xor(mt, 16));
      mt = fmaxf(mt, __shfl_xor(mt, 32));
      const float mn = fmaxf(m_i[qh], mt);
      const float alpha = __expf(m_i[qh] - mn);
      m_i[qh] = mn;
      float p[4][4];
      float ps = 0.f;
#pragma unroll
      for (int sub = 0; sub < 4; sub++)
#pragma unroll
        for (int r = 0; r < 4; r++) { p[sub][r] = __expf(sv[qh][sub][r] - mn); ps += p[sub][r]; }
      ps += __shfl_xor(ps, 16);
      ps += __shfl_xor(ps, 32);
      l_i[qh] = alpha * l_i[qh] + ps;
#pragma unroll
      for (int sub = 0; sub < 4; sub++) {
        ushort4 pk;
        pk.x = f2bf(p[sub][0]); pk.y = f2bf(p[sub][1]);
        pk.z = f2bf(p[sub][2]); pk.w = f2bf(p[sub][3]);
        *(ushort4*)&wm.s.pbuf[qh * 16 + col][sub * 16 + quad * 4] = pk;
      }
      if (quad == 0) wm.s.abuf[qh * 16 + col] = alpha;
    }
    __builtin_amdgcn_s_waitcnt(0xC07F);   // lgkmcnt(0): own-wave LDS visible
    const f32x4 av0 = *(const f32x4*)&wm.s.abuf[quad * 4];
    const f32x4 av1 = *(const f32x4*)&wm.s.abuf[16 + quad * 4];
    short8 pf[2][2];
#pragma unroll
    for (int qh = 0; qh < 2; qh++) {
      pf[qh][0] = *(const short8*)&wm.s.pbuf[qh * 16 + col][quad * 8];
      pf[qh][1] = *(const short8*)&wm.s.pbuf[qh * 16 + col][32 + quad * 8];
    }
#pragma unroll
    for (int c2 = 0; c2 < 4; c2++) {
      const ushort_t* vrow = &vt[((size_t)bh * DK + c2 * 16 + col) * SEQ + skey];
      short8 vf0 = *(const short8*)&vrow[quad * 8];
      short8 vf1 = *(const short8*)&vrow[32 + quad * 8];
#pragma unroll
      for (int r = 0; r < 4; r++) { o[0][c2][r] *= av0[r]; o[1][c2][r] *= av1[r]; }
      o[0][c2] = __builtin_amdgcn_mfma_f32_16x16x32_bf16(pf[0][0], vf0, o[0][c2], 0, 0, 0);
      o[0][c2] = __builtin_amdgcn_mfma_f32_16x16x32_bf16(pf[0][1], vf1, o[0][c2], 0, 0, 0);
      o[1][c2] = __builtin_amdgcn_mfma_f32_16x16x32_bf16(pf[1][0], vf0, o[1][c2], 0, 0, 0);
      o[1][c2] = __builtin_amdgcn_mfma_f32_16x16x32_bf16(pf[1][1], vf1, o[1][c2], 0, 0, 0);
    }
  }

#pragma unroll
  for (int qh = 0; qh < 2; qh++)
#pragma unroll
    for (int c2 = 0; c2 < 4; c2++)
      *(f32x4*)&wm.obuf[qh][c2][lane][0] = o[qh][c2];
  if (quad == 0) {
    mbuf[w][col]      = m_i[0];  mbuf[w][16 + col] = m_i[1];
    lbuf[w][col]      = l_i[0];  lbuf[w][16 + col] = l_i[1];
  }
  __syncthreads();

#pragma unroll
  for (int qh = 0; qh < 2; qh++) {
    float M[4], L[4], sc[4][4];
#pragma unroll
    for (int r = 0; r < 4; r++) {
      int row = qh * 16 + quad * 4 + r;
      float m0 = mbuf[0][row], m1 = mbuf[1][row], m2 = mbuf[2][row], m3 = mbuf[3][row];
      M[r] = fmaxf(fmaxf(m0, m1), fmaxf(m2, m3));
      float e0 = __expf(m0 - M[r]);
      float e1 = __expf(m1 - M[r]);
      float e2 = __expf(m2 - M[r]);
      float e3 = __expf(m3 - M[r]);
      sc[0][r] = e0; sc[1][r] = e1; sc[2][r] = e2; sc[3][r] = e3;
      L[r] = lbuf[0][row] * e0 + lbuf[1][row] * e1 + lbuf[2][row] * e2 + lbuf[3][row] * e3;
    }
    f32x4 oo = {};
#pragma unroll
    for (int wp = 0; wp < 4; wp++) {
      f32x4 tv = *(const f32x4*)&wmem[wp].obuf[qh][w][lane][0];
#pragma unroll
      for (int r = 0; r < 4; r++) oo[r] += tv[r] * sc[wp][r];
    }
#pragma unroll
    for (int r = 0; r < 4; r++) {
      int row = s0 + qh * 16 + quad * 4 + r;
      out[((size_t)(b * SEQ) + row) * D_MODEL + h * DK + w * 16 + col] = f2bf(oo[r] / L[r]);
    }
  }
}

// ---------------- SwiGLU elementwise: u = silu(u)*g ----------------
__global__ __launch_bounds__(256) void silu_mul_kernel(
    ushort_t* __restrict__ u, const ushort_t* __restrict__ g, int n8) {
  int i = blockIdx.x * 256 + threadIdx.x;
  if (i >= n8) return;
  short8 uv = ((const short8*)u)[i];
  short8 gv = ((const short8*)g)[i];
  short8 t;
#pragma unroll
  for (int j = 0; j < 8; j++) {
    float x = bf2f((ushort_t)uv[j]);
    float gg = bf2f((ushort_t)gv[j]);
    float s = x / (1.f + __expf(-x));
    t[j] = (short)f2bf(s * gg);
  }
  ((short8*)u)[i] = t;
}

// ---------------- launcher ----------------
extern "C" void kernel_launch(void* const* d_in, const int* in_sizes, int n_in,
                              void* d_out, int out_size, void* d_ws, size_t ws_size,
                              hipStream_t stream) {
  const float* x  = (const float*)d_in[0];
  const float* g1 = (const float*)d_in[1];
  const float* g2 = (const float*)d_in[2];
  const float* WQ = (const float*)d_in[3];
  const float* WK = (const float*)d_in[4];
  const float* WV = (const float*)d_in[5];
  const float* WO = (const float*)d_in[6];
  const float* W1 = (const float*)d_in[7];
  const float* W2 = (const float*)d_in[8];
  const float* W3 = (const float*)d_in[9];
  float* out = (float*)d_out;

  char* p = (char*)d_ws;
  auto alloc = [&](size_t bytes) {
    char* r = p; p += (bytes + 255) & ~(size_t)255; return r;
  };
  ushort_t* wq  = (ushort_t*)alloc((size_t)D_MODEL * D_MODEL * 2);
  ushort_t* wk  = (ushort_t*)alloc((size_t)D_MODEL * D_MODEL * 2);
  ushort_t* wv  = (ushort_t*)alloc((size_t)D_MODEL * D_MODEL * 2);
  ushort_t* wo  = (ushort_t*)alloc((size_t)D_MODEL * D_MODEL * 2);
  ushort_t* w1b = (ushort_t*)alloc((size_t)D_FF * D_MODEL * 2);
  ushort_t* w2b = (ushort_t*)alloc((size_t)D_FF * D_MODEL * 2);
  ushort_t* w3b = (ushort_t*)alloc((size_t)D_FF * D_MODEL * 2);
  ushort_t* h   = (ushort_t*)alloc((size_t)NTOK * D_MODEL * 2);   // also h2
  ushort_t* qb  = (ushort_t*)alloc((size_t)NTOK * D_MODEL * 2);
  ushort_t* kb  = (ushort_t*)alloc((size_t)NTOK * D_MODEL * 2);
  ushort_t* vb  = (ushort_t*)alloc((size_t)NTOK * D_MODEL * 2);   // later reused as attn out
  ushort_t* vtb = (ushort_t*)alloc((size_t)NTOK * D_MODEL * 2);
  float*    y   = (float*)   alloc((size_t)NTOK * D_MODEL * 4);
  ushort_t* ub  = (ushort_t*)alloc((size_t)NTOK * D_FF * 2);      // silu*g in place
  ushort_t* gb  = (ushort_t*)alloc((size_t)NTOK * D_FF * 2);
  float*    part = (float*)  alloc((size_t)4 * NTOK * D_MODEL * 4);  // split-K partials
  const bool use_split = ((size_t)(p - (char*)d_ws) <= ws_size);

  // ---- weight converts: one launch ----
  const int nb_dd = D_MODEL * D_MODEL / 4 / 256;   // 1024
  const int nb_fd = D_FF * D_MODEL / 4 / 256;      // 2816
  CvtArgs ca;
  ca.src[0]=WQ; ca.dst[0]=wq;  ca.nblk[0]=nb_dd;
  ca.src[1]=WK; ca.dst[1]=wk;  ca.nblk[1]=nb_dd;
  ca.src[2]=WV; ca.dst[2]=wv;  ca.nblk[2]=nb_dd;
  ca.src[3]=WO; ca.dst[3]=wo;  ca.nblk[3]=nb_dd;
  ca.src[4]=W1; ca.dst[4]=w1b; ca.nblk[4]=nb_fd;
  ca.src[5]=W2; ca.dst[5]=w2b; ca.nblk[5]=nb_fd;
  ca.src[6]=W3; ca.dst[6]=w3b; ca.nblk[6]=nb_fd;
  convert_all<<<4 * nb_dd + 3 * nb_fd, 256, 0, stream>>>(ca);

  rmsnorm_kernel<<<NTOK, 256, 0, stream>>>(x, g1, h);

  GemmArgs a1{h, wq, wk, wv, qb, kb, vb, nullptr, NTOK, D_MODEL, D_MODEL};
  gemm128<0><<<dim3(D_MODEL / 128, NTOK / 128, 3), 256, 0, stream>>>(a1);

  rope_kernel<<<(BATCH * SEQ * NHEADS) / 4, 256, 0, stream>>>(qb, kb);
  vtrans_kernel<<<dim3(SEQ / 64, BATCH * NHEADS), 256, 0, stream>>>(vb, vtb);
  attn_kernel<<<dim3((SEQ / 32) * 32, 1), 256, 0, stream>>>(qb, kb, vtb, vb);

  if (use_split) {
    GemmSplitArgs s1{vb, wo, part, D_MODEL, D_MODEL, D_MODEL / 4};
    gemm128_splitk<<<dim3(D_MODEL / 128, NTOK / 128, 4), 256, 0, stream>>>(s1);
    rmsnorm_reduce4<<<NTOK, 256, 0, stream>>>(part, x, g2, y, h);
  } else {
    GemmArgs a2{vb, wo, nullptr, nullptr, y, nullptr, nullptr, x, NTOK, D_MODEL, D_MODEL};
    gemm128<1><<<dim3(D_MODEL / 128, NTOK / 128, 1), 256, 0, stream>>>(a2);
    rmsnorm_kernel<<<NTOK, 256, 0, stream>>>(y, g2, h);
  }

  GemmArgs a3{h, w1b, w3b, nullptr, ub, gb, nullptr, nullptr, NTOK, D_FF, D_MODEL};
  gemm128<0><<<dim3(D_FF / 128, NTOK / 128, 2), 256, 0, stream>>>(a3);

  silu_mul_kernel<<<(NTOK * D_FF / 8) / 256, 256, 0, stream>>>(ub, gb, NTOK * D_FF / 8);

  if (use_split) {
    GemmSplitArgs s2{ub, w2b, part, D_MODEL, D_FF, D_FF / 4};
    gemm128_splitk<<<dim3(D_MODEL / 128, NTOK / 128, 4), 256, 0, stream>>>(s2);
    add_reduce4<<<NTOK * D_MODEL / 4 / 256, 256, 0, stream>>>(part, y, out);
  } else {
    GemmArgs a4{ub, w2b, nullptr, nullptr, out, nullptr, nullptr, y, NTOK, D_MODEL, D_FF};
    gemm128<1><<<dim3(D_MODEL / 128, NTOK / 128, 1), 256, 0, stream>>>(a4);
  }
}

// Round 6
// 427.500 us; speedup vs baseline: 1.4503x; 1.0325x over previous
//
#include <hip/hip_runtime.h>
#include <cstdint>
#include <cstddef>

typedef short short8 __attribute__((ext_vector_type(8)));
typedef float f32x4 __attribute__((ext_vector_type(4)));
typedef unsigned short ushort_t;

#define D_MODEL 1024
#define D_FF    2816
#define SEQ     2048
#define BATCH   2
#define NHEADS  16
#define DK      64
#define NTOK    (BATCH*SEQ)   // 4096

__device__ __forceinline__ float bf2f(ushort_t u) {
  return __builtin_bit_cast(float, (unsigned int)u << 16);
}
__device__ __forceinline__ ushort_t f2bf(float f) {
  unsigned int x = __builtin_bit_cast(unsigned int, f);
  x += 0x7fffu + ((x >> 16) & 1u);   // round-to-nearest-even
  return (ushort_t)(x >> 16);
}

// async global->LDS, 16B per lane. LDS dest = wave-uniform base + lane*16.
__device__ __forceinline__ void gld16(const ushort_t* g, ushort_t* l) {
  __builtin_amdgcn_global_load_lds(
      (const __attribute__((address_space(1))) unsigned int*)g,
      (__attribute__((address_space(3))) unsigned int*)l,
      16, 0, 0);
}

// ---------------- fp32 -> bf16 convert, all 7 weights in one launch ----------------
struct CvtArgs {
  const float* src[7];
  ushort_t* dst[7];
  int nblk[7];   // blocks per segment (n4/256)
};
__global__ __launch_bounds__(256) void convert_all(CvtArgs a) {
  int off = blockIdx.x;
  int seg = 0;
  while (off >= a.nblk[seg]) { off -= a.nblk[seg]; seg++; }   // wave-uniform
  int i = off * 256 + threadIdx.x;
  float4 v = ((const float4*)a.src[seg])[i];
  ushort4 o;
  o.x = f2bf(v.x); o.y = f2bf(v.y); o.z = f2bf(v.z); o.w = f2bf(v.w);
  ((ushort4*)a.dst[seg])[i] = o;
}

// ---------------- RMSNorm (row of 1024) ----------------
__global__ __launch_bounds__(256) void rmsnorm_kernel(
    const float* __restrict__ x, const float* __restrict__ g, ushort_t* __restrict__ out) {
  int row = blockIdx.x;
  int tid = threadIdx.x;
  float4 v = ((const float4*)(x + (size_t)row * D_MODEL))[tid];
  float ss = v.x*v.x + v.y*v.y + v.z*v.z + v.w*v.w;
#pragma unroll
  for (int off = 1; off < 64; off <<= 1) ss += __shfl_xor(ss, off);
  __shared__ float wsum[4];
  if ((tid & 63) == 0) wsum[tid >> 6] = ss;
  __syncthreads();
  float total = wsum[0] + wsum[1] + wsum[2] + wsum[3];
  float rinv = rsqrtf(total * (1.0f / D_MODEL) + 1e-5f);
  float4 gv = ((const float4*)g)[tid];
  ushort4 o;
  o.x = f2bf(v.x * gv.x * rinv);
  o.y = f2bf(v.y * gv.y * rinv);
  o.z = f2bf(v.z * gv.z * rinv);
  o.w = f2bf(v.w * gv.w * rinv);
  ((ushort4*)(out + (size_t)row * D_MODEL))[tid] = o;
}

// ---- y = sum(4 partials) + x; h = rmsnorm(y)*g  (fused WO split-K reduce) ----
__global__ __launch_bounds__(256) void rmsnorm_reduce4(
    const float* __restrict__ part, const float* __restrict__ x,
    const float* __restrict__ g, float* __restrict__ y, ushort_t* __restrict__ h) {
  const int row = blockIdx.x;
  const int tid = threadIdx.x;
  const size_t i = (size_t)row * 256 + tid;           // float4 index
  const size_t MN4 = (size_t)NTOK * (D_MODEL / 4);
  float4 v = ((const float4*)x)[i];
#pragma unroll
  for (int jp = 0; jp < 4; jp++) {
    float4 pv = ((const float4*)part)[jp * MN4 + i];
    v.x += pv.x; v.y += pv.y; v.z += pv.z; v.w += pv.w;
  }
  ((float4*)y)[i] = v;
  float ss = v.x*v.x + v.y*v.y + v.z*v.z + v.w*v.w;
#pragma unroll
  for (int off = 1; off < 64; off <<= 1) ss += __shfl_xor(ss, off);
  __shared__ float wsum[4];
  if ((tid & 63) == 0) wsum[tid >> 6] = ss;
  __syncthreads();
  float total = wsum[0] + wsum[1] + wsum[2] + wsum[3];
  float rinv = rsqrtf(total * (1.0f / D_MODEL) + 1e-5f);
  float4 gv = ((const float4*)g)[tid];
  ushort4 o;
  o.x = f2bf(v.x * gv.x * rinv);
  o.y = f2bf(v.y * gv.y * rinv);
  o.z = f2bf(v.z * gv.z * rinv);
  o.w = f2bf(v.w * gv.w * rinv);
  ((ushort4*)(h + (size_t)row * D_MODEL))[tid] = o;
}

// ---- out = sum(4 partials) + y  (W2 split-K reduce + final residual) ----
__global__ __launch_bounds__(256) void add_reduce4(
    const float* __restrict__ part, const float* __restrict__ y, float* __restrict__ out) {
  const size_t i = (size_t)blockIdx.x * 256 + threadIdx.x;
  const size_t MN4 = (size_t)NTOK * (D_MODEL / 4);
  float4 v = ((const float4*)y)[i];
#pragma unroll
  for (int jp = 0; jp < 4; jp++) {
    float4 pv = ((const float4*)part)[jp * MN4 + i];
    v.x += pv.x; v.y += pv.y; v.z += pv.z; v.w += pv.w;
  }
  ((float4*)out)[i] = v;
}

// ---------------- GEMM: C[M,N] = A[M,K] * B[N,K]^T ----------------
// m97 structure: 128x128 tile, BK=32, 4 waves each 64x64, global_load_lds w=16.
struct GemmArgs {
  const ushort_t* A;
  const ushort_t* B0; const ushort_t* B1; const ushort_t* B2;
  void* C0; void* C1; void* C2;
  const float* resid;   // EPI==1
  int M, N, K;
};

template<int EPI>  // 0: store bf16; 1: store fp32 = acc + resid
__global__ __launch_bounds__(256) void gemm128(GemmArgs args) {
  const ushort_t* B = blockIdx.z == 0 ? args.B0 : (blockIdx.z == 1 ? args.B1 : args.B2);
  void* C = blockIdx.z == 0 ? args.C0 : (blockIdx.z == 1 ? args.C1 : args.C2);
  const int N = args.N, K = args.K;
  __shared__ __align__(16) ushort_t sA[128 * 32];
  __shared__ __align__(16) ushort_t sB[128 * 32];
  const int tid  = threadIdx.x;
  const int w    = tid >> 6;
  const int lane = tid & 63;
  const int col  = lane & 15;
  const int quad = lane >> 4;
  const int waveM = (w >> 1) * 64;
  const int waveN = (w & 1) * 64;
  const int bm = blockIdx.y * 128;
  const int bn = blockIdx.x * 128;

  f32x4 acc[4][4] = {};

  const int srow = tid >> 2;           // 0..63
  const int scol = (tid & 3) * 8;
  const ushort_t* gA = args.A + (size_t)(bm + srow) * K + scol;
  const ushort_t* gB = B      + (size_t)(bn + srow) * K + scol;
  ushort_t* lA = sA + tid * 8;         // byte off = tid*16
  ushort_t* lB = sB + tid * 8;
  const size_t rstep = (size_t)64 * K;

  for (int k0 = 0; k0 < K; k0 += 32) {
    gld16(gA + k0,         lA);
    gld16(gA + k0 + rstep, lA + 2048);   // rows 64..127 -> +4096 B
    gld16(gB + k0,         lB);
    gld16(gB + k0 + rstep, lB + 2048);
    __syncthreads();                     // drains vmcnt -> LDS ready
    short8 af[4], bf[4];
#pragma unroll
    for (int mi = 0; mi < 4; mi++)
      af[mi] = *(const short8*)&sA[(waveM + mi * 16 + col) * 32 + quad * 8];
#pragma unroll
    for (int ni = 0; ni < 4; ni++)
      bf[ni] = *(const short8*)&sB[(waveN + ni * 16 + col) * 32 + quad * 8];
#pragma unroll
    for (int mi = 0; mi < 4; mi++)
#pragma unroll
      for (int ni = 0; ni < 4; ni++)
        acc[mi][ni] = __builtin_amdgcn_mfma_f32_16x16x32_bf16(af[mi], bf[ni], acc[mi][ni], 0, 0, 0);
    __syncthreads();                     // all reads done before next stage
  }

#pragma unroll
  for (int mi = 0; mi < 4; mi++) {
    int r0 = bm + waveM + mi * 16 + quad * 4;
#pragma unroll
    for (int ni = 0; ni < 4; ni++) {
      int c0 = bn + waveN + ni * 16 + col;
#pragma unroll
      for (int r = 0; r < 4; r++) {
        size_t idx = (size_t)(r0 + r) * N + c0;
        if (EPI == 0) ((ushort_t*)C)[idx] = f2bf(acc[mi][ni][r]);
        else          ((float*)C)[idx]    = acc[mi][ni][r] + args.resid[idx];
      }
    }
  }
}

// ---- split-K variant: grid.z = 4 K-chunks, fp32 partials to C[z][M*N] ----
struct GemmSplitArgs {
  const ushort_t* A; const ushort_t* B;
  float* C;           // 4 x (NTOK*N) fp32 partials
  int N, K, kchunk;   // kchunk = K/4, multiple of 32
};

__global__ __launch_bounds__(256) void gemm128_splitk(GemmSplitArgs args) {
  const int N = args.N, K = args.K;
  const int kbeg = blockIdx.z * args.kchunk;
  const int kend = kbeg + args.kchunk;
  __shared__ __align__(16) ushort_t sA[128 * 32];
  __shared__ __align__(16) ushort_t sB[128 * 32];
  const int tid  = threadIdx.x;
  const int w    = tid >> 6;
  const int lane = tid & 63;
  const int col  = lane & 15;
  const int quad = lane >> 4;
  const int waveM = (w >> 1) * 64;
  const int waveN = (w & 1) * 64;
  const int bm = blockIdx.y * 128;
  const int bn = blockIdx.x * 128;

  f32x4 acc[4][4] = {};

  const int srow = tid >> 2;
  const int scol = (tid & 3) * 8;
  const ushort_t* gA = args.A + (size_t)(bm + srow) * K + scol;
  const ushort_t* gB = args.B + (size_t)(bn + srow) * K + scol;
  ushort_t* lA = sA + tid * 8;
  ushort_t* lB = sB + tid * 8;
  const size_t rstep = (size_t)64 * K;

  for (int k0 = kbeg; k0 < kend; k0 += 32) {
    gld16(gA + k0,         lA);
    gld16(gA + k0 + rstep, lA + 2048);
    gld16(gB + k0,         lB);
    gld16(gB + k0 + rstep, lB + 2048);
    __syncthreads();
    short8 af[4], bf[4];
#pragma unroll
    for (int mi = 0; mi < 4; mi++)
      af[mi] = *(const short8*)&sA[(waveM + mi * 16 + col) * 32 + quad * 8];
#pragma unroll
    for (int ni = 0; ni < 4; ni++)
      bf[ni] = *(const short8*)&sB[(waveN + ni * 16 + col) * 32 + quad * 8];
#pragma unroll
    for (int mi = 0; mi < 4; mi++)
#pragma unroll
      for (int ni = 0; ni < 4; ni++)
        acc[mi][ni] = __builtin_amdgcn_mfma_f32_16x16x32_bf16(af[mi], bf[ni], acc[mi][ni], 0, 0, 0);
    __syncthreads();
  }

  float* C = args.C + (size_t)blockIdx.z * ((size_t)NTOK * N);
#pragma unroll
  for (int mi = 0; mi < 4; mi++) {
    int r0 = bm + waveM + mi * 16 + quad * 4;
#pragma unroll
    for (int ni = 0; ni < 4; ni++) {
      int c0 = bn + waveN + ni * 16 + col;
#pragma unroll
      for (int r = 0; r < 4; r++)
        C[(size_t)(r0 + r) * N + c0] = acc[mi][ni][r];
    }
  }
}

// ---------------- RoPE (q,k in place), one wave per (b,s,h) ----------------
// q additionally pre-scaled by dk^-1/2 = 0.125 (exact pow2) so attention
// skips the per-score scaling.
__global__ __launch_bounds__(256) void rope_kernel(
    ushort_t* __restrict__ q, ushort_t* __restrict__ k) {
  int item = blockIdx.x * 4 + (threadIdx.x >> 6);   // 0..65535
  int lane = threadIdx.x & 63;
  int h = item & 15;
  int s = (item >> 4) & (SEQ - 1);
  int b = item >> 15;
  size_t idx = ((size_t)(b * SEQ + s)) * D_MODEL + h * DK + lane;
  int p = lane >> 1;
  float inv = expf(-(float)p * (9.210340372f / 32.0f));
  float ang = (float)s * inv;
  float cs = cosf(ang), sn = sinf(ang);
  float qv = bf2f(q[idx]);
  float kv = bf2f(k[idx]);
  float qp = __shfl_xor(qv, 1);
  float kp = __shfl_xor(kv, 1);
  float sgn = (lane & 1) ? sn : -sn;
  q[idx] = f2bf((qv * cs + qp * sgn) * 0.125f);
  k[idx] = f2bf(kv * cs + kp * sgn);
}

// ---------------- V transpose: [B,S,H*dk] -> [B,H,dk,S] ----------------
__global__ __launch_bounds__(256) void vtrans_kernel(
    const ushort_t* __restrict__ v, ushort_t* __restrict__ vt) {
  int bh = blockIdx.y;
  int b = bh >> 4, h = bh & 15;
  int s0 = blockIdx.x * 64;
  __shared__ ushort_t tile[64][65];
  for (int i = threadIdx.x; i < 64 * 64; i += 256) {
    int sl = i >> 6, dl = i & 63;
    tile[dl][sl] = v[((size_t)(b * SEQ + s0 + sl)) * D_MODEL + h * DK + dl];
  }
  __syncthreads();
  for (int i = threadIdx.x; i < 64 * 64; i += 256) {
    int dl = i >> 6, sl = i & 63;
    vt[((size_t)bh * DK + dl) * SEQ + s0 + sl] = tile[dl][sl];
  }
}

// ---------------- flash attention, causal, q-tile 32, XCD-swizzled, pipelined ----------------
// grid 2048 (1D). bh = blockIdx & 31 (head -> XCD affinity via %8: K+V for 4
// heads = 2 MB resident per 4 MB XCD L2). Block = 32 q-rows; 4 waves split keys
// in 64-key tiles; merged via LDS log-sum-exp. Scores transposed (S^T = K*Q^T).
// Pipelining: V loads issued at tile start (in flight during QK+softmax);
// next tile's K prefetched right after QK MFMAs consume the current fragments.
struct WaveMem {
  union {
    struct {
      ushort_t pbuf[32][72];
      float abuf[32];
    } s;
    float obuf[2][4][64][4];
  };
};

__global__ __launch_bounds__(256) void attn_kernel(
    const ushort_t* __restrict__ q, const ushort_t* __restrict__ k,
    const ushort_t* __restrict__ vt, ushort_t* __restrict__ out) {
  const int bidx = blockIdx.x;
  const int bh = bidx & 31;              // head -> XCD affinity via %8
  const int b = bh >> 4, h = bh & 15;
  const int t = 63 - (bidx >> 5);        // longest-first
  const int s0 = t * 32;
  const int w = threadIdx.x >> 6, lane = threadIdx.x & 63;
  const int col = lane & 15, quad = lane >> 4;
  const size_t base = ((size_t)(b * SEQ)) * D_MODEL + h * DK;

  short8 qf[2][2];
#pragma unroll
  for (int qh = 0; qh < 2; qh++)
#pragma unroll
    for (int kk = 0; kk < 2; kk++)
      qf[qh][kk] = *(const short8*)&q[base + (size_t)(s0 + qh * 16 + col) * D_MODEL + kk * 32 + quad * 8];

  f32x4 o[2][4] = {};
  float m_i[2] = {-__builtin_inff(), -__builtin_inff()};
  float l_i[2] = {0.f, 0.f};

  __shared__ __align__(16) WaveMem wmem[4];
  __shared__ float mbuf[4][32];
  __shared__ float lbuf[4][32];
  WaveMem& wm = wmem[w];

  const int ntiles = (s0 + 32 + 63) >> 6;
  short8 kf[2][4];   // current tile's K fragments (prefetched)
  if (w < ntiles) {
    const int skey = w * 64;
#pragma unroll
    for (int kk = 0; kk < 2; kk++)
#pragma unroll
      for (int sub = 0; sub < 4; sub++)
        kf[kk][sub] = *(const short8*)&k[base + (size_t)(skey + sub * 16 + col) * D_MODEL + kk * 32 + quad * 8];
  }

  for (int jt = w; jt < ntiles; jt += 4) {
    const int skey = jt * 64;
    // V loads for THIS tile, issued before the compute chain consumes them
    short8 vf[4][2];
#pragma unroll
    for (int c2 = 0; c2 < 4; c2++) {
      const ushort_t* vrow = &vt[((size_t)bh * DK + c2 * 16 + col) * SEQ + skey];
      vf[c2][0] = *(const short8*)&vrow[quad * 8];
      vf[c2][1] = *(const short8*)&vrow[32 + quad * 8];
    }
    f32x4 S[2][4] = {};
#pragma unroll
    for (int kk = 0; kk < 2; kk++) {
#pragma unroll
      for (int sub = 0; sub < 4; sub++) {
        S[0][sub] = __builtin_amdgcn_mfma_f32_16x16x32_bf16(kf[kk][sub], qf[0][kk], S[0][sub], 0, 0, 0);
        S[1][sub] = __builtin_amdgcn_mfma_f32_16x16x32_bf16(kf[kk][sub], qf[1][kk], S[1][sub], 0, 0, 0);
      }
    }
    // prefetch NEXT tile's K (overlaps softmax + PV below)
    const int jn = jt + 4;
    if (jn < ntiles) {
      const int skn = jn * 64;
#pragma unroll
      for (int kk = 0; kk < 2; kk++)
#pragma unroll
        for (int sub = 0; sub < 4; sub++)
          kf[kk][sub] = *(const short8*)&k[base + (size_t)(skn + sub * 16 + col) * D_MODEL + kk * 32 + quad * 8];
    }
    // lane holds S^T[key = skey+sub*16+quad*4+r][query = s0+qh*16+col]
    float sv[2][4][4];
#pragma unroll
    for (int qh = 0; qh < 2; qh++)
#pragma unroll
      for (int sub = 0; sub < 4; sub++)
#pragma unroll
        for (int r = 0; r < 4; r++) sv[qh][sub][r] = S[qh][sub][r];
    if (skey + 63 > s0) {   // causal mask: key > query -> -inf
#pragma unroll
      for (int qh = 0; qh < 2; qh++) {
        const int kb = skey + quad * 4 - s0 - qh * 16 - col;
#pragma unroll
        for (int sub = 0; sub < 4; sub++)
#pragma unroll
          for (int r = 0; r < 4; r++)
            if (kb + sub * 16 + r > 0) sv[qh][sub][r] = -__builtin_inff();
      }
    }
#pragma unroll
    for (int qh = 0; qh < 2; qh++) {
      float mt = sv[qh][0][0];
#pragma unroll
      for (int sub = 0; sub < 4; sub++)
#pragma unroll
        for (int r = 0; r < 4; r++) mt = fmaxf(mt, sv[qh][sub][r]);
      mt = fmaxf(mt, __shfl_xor(mt, 16));
      mt = fmaxf(mt, __shfl_xor(mt, 32));
      const float mn = fmaxf(m_i[qh], mt);
      const float alpha = __expf(m_i[qh] - mn);
      m_i[qh] = mn;
      float p[4][4];
      float ps = 0.f;
#pragma unroll
      for (int sub = 0; sub < 4; sub++)
#pragma unroll
        for (int r = 0; r < 4; r++) { p[sub][r] = __expf(sv[qh][sub][r] - mn); ps += p[sub][r]; }
      ps += __shfl_xor(ps, 16);
      ps += __shfl_xor(ps, 32);
      l_i[qh] = alpha * l_i[qh] + ps;
#pragma unroll
      for (int sub = 0; sub < 4; sub++) {
        ushort4 pk;
        pk.x = f2bf(p[sub][0]); pk.y = f2bf(p[sub][1]);
        pk.z = f2bf(p[sub][2]); pk.w = f2bf(p[sub][3]);
        *(ushort4*)&wm.s.pbuf[qh * 16 + col][sub * 16 + quad * 4] = pk;
      }
      if (quad == 0) wm.s.abuf[qh * 16 + col] = alpha;
    }
    __builtin_amdgcn_s_waitcnt(0xC07F);   // lgkmcnt(0): own-wave LDS visible
    const f32x4 av0 = *(const f32x4*)&wm.s.abuf[quad * 4];
    const f32x4 av1 = *(const f32x4*)&wm.s.abuf[16 + quad * 4];
    short8 pf[2][2];
#pragma unroll
    for (int qh = 0; qh < 2; qh++) {
      pf[qh][0] = *(const short8*)&wm.s.pbuf[qh * 16 + col][quad * 8];
      pf[qh][1] = *(const short8*)&wm.s.pbuf[qh * 16 + col][32 + quad * 8];
    }
#pragma unroll
    for (int c2 = 0; c2 < 4; c2++) {
#pragma unroll
      for (int r = 0; r < 4; r++) { o[0][c2][r] *= av0[r]; o[1][c2][r] *= av1[r]; }
      o[0][c2] = __builtin_amdgcn_mfma_f32_16x16x32_bf16(pf[0][0], vf[c2][0], o[0][c2], 0, 0, 0);
      o[0][c2] = __builtin_amdgcn_mfma_f32_16x16x32_bf16(pf[0][1], vf[c2][1], o[0][c2], 0, 0, 0);
      o[1][c2] = __builtin_amdgcn_mfma_f32_16x16x32_bf16(pf[1][0], vf[c2][0], o[1][c2], 0, 0, 0);
      o[1][c2] = __builtin_amdgcn_mfma_f32_16x16x32_bf16(pf[1][1], vf[c2][1], o[1][c2], 0, 0, 0);
    }
  }

#pragma unroll
  for (int qh = 0; qh < 2; qh++)
#pragma unroll
    for (int c2 = 0; c2 < 4; c2++)
      *(f32x4*)&wm.obuf[qh][c2][lane][0] = o[qh][c2];
  if (quad == 0) {
    mbuf[w][col]      = m_i[0];  mbuf[w][16 + col] = m_i[1];
    lbuf[w][col]      = l_i[0];  lbuf[w][16 + col] = l_i[1];
  }
  __syncthreads();

#pragma unroll
  for (int qh = 0; qh < 2; qh++) {
    float M[4], L[4], sc[4][4];
#pragma unroll
    for (int r = 0; r < 4; r++) {
      int row = qh * 16 + quad * 4 + r;
      float m0 = mbuf[0][row], m1 = mbuf[1][row], m2 = mbuf[2][row], m3 = mbuf[3][row];
      M[r] = fmaxf(fmaxf(m0, m1), fmaxf(m2, m3));
      float e0 = __expf(m0 - M[r]);
      float e1 = __expf(m1 - M[r]);
      float e2 = __expf(m2 - M[r]);
      float e3 = __expf(m3 - M[r]);
      sc[0][r] = e0; sc[1][r] = e1; sc[2][r] = e2; sc[3][r] = e3;
      L[r] = lbuf[0][row] * e0 + lbuf[1][row] * e1 + lbuf[2][row] * e2 + lbuf[3][row] * e3;
    }
    f32x4 oo = {};
#pragma unroll
    for (int wp = 0; wp < 4; wp++) {
      f32x4 tv = *(const f32x4*)&wmem[wp].obuf[qh][w][lane][0];
#pragma unroll
      for (int r = 0; r < 4; r++) oo[r] += tv[r] * sc[wp][r];
    }
#pragma unroll
    for (int r = 0; r < 4; r++) {
      int row = s0 + qh * 16 + quad * 4 + r;
      out[((size_t)(b * SEQ) + row) * D_MODEL + h * DK + w * 16 + col] = f2bf(oo[r] / L[r]);
    }
  }
}

// ---------------- SwiGLU elementwise: u = silu(u)*g ----------------
__global__ __launch_bounds__(256) void silu_mul_kernel(
    ushort_t* __restrict__ u, const ushort_t* __restrict__ g, int n8) {
  int i = blockIdx.x * 256 + threadIdx.x;
  if (i >= n8) return;
  short8 uv = ((const short8*)u)[i];
  short8 gv = ((const short8*)g)[i];
  short8 t;
#pragma unroll
  for (int j = 0; j < 8; j++) {
    float x = bf2f((ushort_t)uv[j]);
    float gg = bf2f((ushort_t)gv[j]);
    float s = x / (1.f + __expf(-x));
    t[j] = (short)f2bf(s * gg);
  }
  ((short8*)u)[i] = t;
}

// ---------------- launcher ----------------
extern "C" void kernel_launch(void* const* d_in, const int* in_sizes, int n_in,
                              void* d_out, int out_size, void* d_ws, size_t ws_size,
                              hipStream_t stream) {
  const float* x  = (const float*)d_in[0];
  const float* g1 = (const float*)d_in[1];
  const float* g2 = (const float*)d_in[2];
  const float* WQ = (const float*)d_in[3];
  const float* WK = (const float*)d_in[4];
  const float* WV = (const float*)d_in[5];
  const float* WO = (const float*)d_in[6];
  const float* W1 = (const float*)d_in[7];
  const float* W2 = (const float*)d_in[8];
  const float* W3 = (const float*)d_in[9];
  float* out = (float*)d_out;

  char* p = (char*)d_ws;
  auto alloc = [&](size_t bytes) {
    char* r = p; p += (bytes + 255) & ~(size_t)255; return r;
  };
  ushort_t* wq  = (ushort_t*)alloc((size_t)D_MODEL * D_MODEL * 2);
  ushort_t* wk  = (ushort_t*)alloc((size_t)D_MODEL * D_MODEL * 2);
  ushort_t* wv  = (ushort_t*)alloc((size_t)D_MODEL * D_MODEL * 2);
  ushort_t* wo  = (ushort_t*)alloc((size_t)D_MODEL * D_MODEL * 2);
  ushort_t* w1b = (ushort_t*)alloc((size_t)D_FF * D_MODEL * 2);
  ushort_t* w2b = (ushort_t*)alloc((size_t)D_FF * D_MODEL * 2);
  ushort_t* w3b = (ushort_t*)alloc((size_t)D_FF * D_MODEL * 2);
  ushort_t* h   = (ushort_t*)alloc((size_t)NTOK * D_MODEL * 2);   // also h2
  ushort_t* qb  = (ushort_t*)alloc((size_t)NTOK * D_MODEL * 2);
  ushort_t* kb  = (ushort_t*)alloc((size_t)NTOK * D_MODEL * 2);
  ushort_t* vb  = (ushort_t*)alloc((size_t)NTOK * D_MODEL * 2);   // later reused as attn out
  ushort_t* vtb = (ushort_t*)alloc((size_t)NTOK * D_MODEL * 2);
  float*    y   = (float*)   alloc((size_t)NTOK * D_MODEL * 4);
  ushort_t* ub  = (ushort_t*)alloc((size_t)NTOK * D_FF * 2);      // silu*g in place
  ushort_t* gb  = (ushort_t*)alloc((size_t)NTOK * D_FF * 2);
  float*    part = (float*)  alloc((size_t)4 * NTOK * D_MODEL * 4);  // split-K partials
  const bool use_split = ((size_t)(p - (char*)d_ws) <= ws_size);

  // ---- weight converts: one launch ----
  const int nb_dd = D_MODEL * D_MODEL / 4 / 256;   // 1024
  const int nb_fd = D_FF * D_MODEL / 4 / 256;      // 2816
  CvtArgs ca;
  ca.src[0]=WQ; ca.dst[0]=wq;  ca.nblk[0]=nb_dd;
  ca.src[1]=WK; ca.dst[1]=wk;  ca.nblk[1]=nb_dd;
  ca.src[2]=WV; ca.dst[2]=wv;  ca.nblk[2]=nb_dd;
  ca.src[3]=WO; ca.dst[3]=wo;  ca.nblk[3]=nb_dd;
  ca.src[4]=W1; ca.dst[4]=w1b; ca.nblk[4]=nb_fd;
  ca.src[5]=W2; ca.dst[5]=w2b; ca.nblk[5]=nb_fd;
  ca.src[6]=W3; ca.dst[6]=w3b; ca.nblk[6]=nb_fd;
  convert_all<<<4 * nb_dd + 3 * nb_fd, 256, 0, stream>>>(ca);

  rmsnorm_kernel<<<NTOK, 256, 0, stream>>>(x, g1, h);

  GemmArgs a1{h, wq, wk, wv, qb, kb, vb, nullptr, NTOK, D_MODEL, D_MODEL};
  gemm128<0><<<dim3(D_MODEL / 128, NTOK / 128, 3), 256, 0, stream>>>(a1);

  rope_kernel<<<(BATCH * SEQ * NHEADS) / 4, 256, 0, stream>>>(qb, kb);
  vtrans_kernel<<<dim3(SEQ / 64, BATCH * NHEADS), 256, 0, stream>>>(vb, vtb);
  attn_kernel<<<dim3((SEQ / 32) * 32, 1), 256, 0, stream>>>(qb, kb, vtb, vb);

  if (use_split) {
    GemmSplitArgs s1{vb, wo, part, D_MODEL, D_MODEL, D_MODEL / 4};
    gemm128_splitk<<<dim3(D_MODEL / 128, NTOK / 128, 4), 256, 0, stream>>>(s1);
    rmsnorm_reduce4<<<NTOK, 256, 0, stream>>>(part, x, g2, y, h);
  } else {
    GemmArgs a2{vb, wo, nullptr, nullptr, y, nullptr, nullptr, x, NTOK, D_MODEL, D_MODEL};
    gemm128<1><<<dim3(D_MODEL / 128, NTOK / 128, 1), 256, 0, stream>>>(a2);
    rmsnorm_kernel<<<NTOK, 256, 0, stream>>>(y, g2, h);
  }

  GemmArgs a3{h, w1b, w3b, nullptr, ub, gb, nullptr, nullptr, NTOK, D_FF, D_MODEL};
  gemm128<0><<<dim3(D_FF / 128, NTOK / 128, 2), 256, 0, stream>>>(a3);

  silu_mul_kernel<<<(NTOK * D_FF / 8) / 256, 256, 0, stream>>>(ub, gb, NTOK * D_FF / 8);

  if (use_split) {
    GemmSplitArgs s2{ub, w2b, part, D_MODEL, D_FF, D_FF / 4};
    gemm128_splitk<<<dim3(D_MODEL / 128, NTOK / 128, 4), 256, 0, stream>>>(s2);
    add_reduce4<<<NTOK * D_MODEL / 4 / 256, 256, 0, stream>>>(part, y, out);
  } else {
    GemmArgs a4{ub, w2b, nullptr, nullptr, out, nullptr, nullptr, y, NTOK, D_MODEL, D_FF};
    gemm128<1><<<dim3(D_MODEL / 128, NTOK / 128, 1), 256, 0, stream>>>(a4);
  }
}